// Round 1
// baseline (6485.357 us; speedup 1.0000x reference)
//
#include <hip/hip_runtime.h>

#define CDIM 128
#define HDIM 512
#define NB 2
#define NNODES 50000
#define NEDGES 800000
#define ROWS (NB * NNODES)

#define NPB 32   // nodes per block in MLP
#define HC 64    // hidden chunk
#define MT 256   // threads per block

__global__ void copy_f4(const float4* __restrict__ s, float4* __restrict__ d, int n4) {
  int i = blockIdx.x * blockDim.x + threadIdx.x;
  int str = gridDim.x * blockDim.x;
  for (; i < n4; i += str) d[i] = s[i];
}

// h[b, dst, :] += x[b, src, :]; 32 threads per (b, edge), float4 each
__global__ void scatter_add_k(const float* __restrict__ x, const int* __restrict__ ei,
                              float* __restrict__ h) {
  long long g = (long long)blockIdx.x * MT + threadIdx.x;
  int q = (int)(g & 31);
  long long t = g >> 5;
  if (t >= (long long)NB * NEDGES) return;
  int e = (int)(t % NEDGES);
  int b = (int)(t / NEDGES);
  int s = ei[e];           // src row
  int d = ei[NEDGES + e];  // dst row
  const float4 v = *(const float4*)(x + ((size_t)b * NNODES + s) * CDIM + q * 4);
  float* hp = h + ((size_t)b * NNODES + d) * CDIM + q * 4;
  atomicAdd(hp + 0, v.x);
  atomicAdd(hp + 1, v.y);
  atomicAdd(hp + 2, v.z);
  atomicAdd(hp + 3, v.w);
}

// out = relu(h @ W1 + b1) @ W2 + b2, fused per 32-node tile
__global__ __launch_bounds__(MT) void mlp_fused(
    const float* __restrict__ hin, const float* __restrict__ W1,
    const float* __restrict__ b1, const float* __restrict__ W2,
    const float* __restrict__ b2, float* __restrict__ out) {
  __shared__ float sh[NPB][CDIM + 4];       // 32 x 132  (16.9 KB)
  __shared__ float st[NPB][HC + 4];         // 32 x 68   (8.7 KB)
  __shared__ float wbuf[CDIM * (HC + 4)];   // W1 chunk [128][68] / W2 chunk [64][132] (34 KB)

  const int tid = threadIdx.x;
  const size_t r0 = (size_t)blockIdx.x * NPB;

  // stage h tile (contiguous rows)
  for (int i = tid; i < NPB * (CDIM / 4); i += MT) {
    int n = i >> 5, c4 = i & 31;
    *(float4*)&sh[n][c4 * 4] = *(const float4*)(hin + (r0 + n) * CDIM + c4 * 4);
  }

  const int ct = tid & 31, nt = tid >> 5;    // GEMM2 map: c = ct*4, n = nt*4
  const int jt = tid & 15, nt2 = tid >> 4;   // GEMM1 map: j = jt*4, n = nt2*2

  float acc[4][4] = {{0.f}};  // [nk][ck]

  for (int chunk = 0; chunk < HDIM / HC; ++chunk) {
    const int j0 = chunk * HC;
    __syncthreads();  // prior GEMM2 done with wbuf/st
    // stage W1[:, j0:j0+64] -> wbuf[c*(HC+4) + j]
    for (int i = tid; i < CDIM * (HC / 4); i += MT) {
      int c = i >> 4, jq = i & 15;
      *(float4*)&wbuf[c * (HC + 4) + jq * 4] =
          *(const float4*)(W1 + (size_t)c * HDIM + j0 + jq * 4);
    }
    __syncthreads();

    // GEMM1: t[n][j] = sum_c h[n][c] * W1[c][j]
    float tacc[4][2] = {{0.f}};  // [jk][nk]
#pragma unroll 4
    for (int c4 = 0; c4 < CDIM / 4; ++c4) {
      float4 h0 = *(const float4*)&sh[nt2 * 2 + 0][c4 * 4];
      float4 h1 = *(const float4*)&sh[nt2 * 2 + 1][c4 * 4];
      float4 w0 = *(const float4*)&wbuf[(c4 * 4 + 0) * (HC + 4) + jt * 4];
      float4 w1 = *(const float4*)&wbuf[(c4 * 4 + 1) * (HC + 4) + jt * 4];
      float4 w2 = *(const float4*)&wbuf[(c4 * 4 + 2) * (HC + 4) + jt * 4];
      float4 w3 = *(const float4*)&wbuf[(c4 * 4 + 3) * (HC + 4) + jt * 4];
      tacc[0][0] += h0.x * w0.x + h0.y * w1.x + h0.z * w2.x + h0.w * w3.x;
      tacc[1][0] += h0.x * w0.y + h0.y * w1.y + h0.z * w2.y + h0.w * w3.y;
      tacc[2][0] += h0.x * w0.z + h0.y * w1.z + h0.z * w2.z + h0.w * w3.z;
      tacc[3][0] += h0.x * w0.w + h0.y * w1.w + h0.z * w2.w + h0.w * w3.w;
      tacc[0][1] += h1.x * w0.x + h1.y * w1.x + h1.z * w2.x + h1.w * w3.x;
      tacc[1][1] += h1.x * w0.y + h1.y * w1.y + h1.z * w2.y + h1.w * w3.y;
      tacc[2][1] += h1.x * w0.z + h1.y * w1.z + h1.z * w2.z + h1.w * w3.z;
      tacc[3][1] += h1.x * w0.w + h1.y * w1.w + h1.z * w2.w + h1.w * w3.w;
    }
    // relu + b1 -> st
    {
      float4 b1v = *(const float4*)(b1 + j0 + jt * 4);
      float4 o0, o1;
      o0.x = fmaxf(tacc[0][0] + b1v.x, 0.f);
      o0.y = fmaxf(tacc[1][0] + b1v.y, 0.f);
      o0.z = fmaxf(tacc[2][0] + b1v.z, 0.f);
      o0.w = fmaxf(tacc[3][0] + b1v.w, 0.f);
      o1.x = fmaxf(tacc[0][1] + b1v.x, 0.f);
      o1.y = fmaxf(tacc[1][1] + b1v.y, 0.f);
      o1.z = fmaxf(tacc[2][1] + b1v.z, 0.f);
      o1.w = fmaxf(tacc[3][1] + b1v.w, 0.f);
      *(float4*)&st[nt2 * 2 + 0][jt * 4] = o0;
      *(float4*)&st[nt2 * 2 + 1][jt * 4] = o1;
    }
    __syncthreads();  // GEMM1 done with wbuf, st ready
    // stage W2[j0:j0+64, :] -> wbuf[j*(CDIM+4) + c]
    for (int i = tid; i < HC * (CDIM / 4); i += MT) {
      int j = i >> 5, cq = i & 31;
      *(float4*)&wbuf[j * (CDIM + 4) + cq * 4] =
          *(const float4*)(W2 + (size_t)(j0 + j) * CDIM + cq * 4);
    }
    __syncthreads();

    // GEMM2: out[n][c] += sum_j t[n][j] * W2[j][c]
#pragma unroll 4
    for (int j4 = 0; j4 < HC / 4; ++j4) {
      float4 t0 = *(const float4*)&st[nt * 4 + 0][j4 * 4];
      float4 t1 = *(const float4*)&st[nt * 4 + 1][j4 * 4];
      float4 t2 = *(const float4*)&st[nt * 4 + 2][j4 * 4];
      float4 t3 = *(const float4*)&st[nt * 4 + 3][j4 * 4];
      float4 v0 = *(const float4*)&wbuf[(j4 * 4 + 0) * (CDIM + 4) + ct * 4];
      float4 v1 = *(const float4*)&wbuf[(j4 * 4 + 1) * (CDIM + 4) + ct * 4];
      float4 v2 = *(const float4*)&wbuf[(j4 * 4 + 2) * (CDIM + 4) + ct * 4];
      float4 v3 = *(const float4*)&wbuf[(j4 * 4 + 3) * (CDIM + 4) + ct * 4];
      acc[0][0] += t0.x * v0.x + t0.y * v1.x + t0.z * v2.x + t0.w * v3.x;
      acc[0][1] += t0.x * v0.y + t0.y * v1.y + t0.z * v2.y + t0.w * v3.y;
      acc[0][2] += t0.x * v0.z + t0.y * v1.z + t0.z * v2.z + t0.w * v3.z;
      acc[0][3] += t0.x * v0.w + t0.y * v1.w + t0.z * v2.w + t0.w * v3.w;
      acc[1][0] += t1.x * v0.x + t1.y * v1.x + t1.z * v2.x + t1.w * v3.x;
      acc[1][1] += t1.x * v0.y + t1.y * v1.y + t1.z * v2.y + t1.w * v3.y;
      acc[1][2] += t1.x * v0.z + t1.y * v1.z + t1.z * v2.z + t1.w * v3.z;
      acc[1][3] += t1.x * v0.w + t1.y * v1.w + t1.z * v2.w + t1.w * v3.w;
      acc[2][0] += t2.x * v0.x + t2.y * v1.x + t2.z * v2.x + t2.w * v3.x;
      acc[2][1] += t2.x * v0.y + t2.y * v1.y + t2.z * v2.y + t2.w * v3.y;
      acc[2][2] += t2.x * v0.z + t2.y * v1.z + t2.z * v2.z + t2.w * v3.z;
      acc[2][3] += t2.x * v0.w + t2.y * v1.w + t2.z * v2.w + t2.w * v3.w;
      acc[3][0] += t3.x * v0.x + t3.y * v1.x + t3.z * v2.x + t3.w * v3.x;
      acc[3][1] += t3.x * v0.y + t3.y * v1.y + t3.z * v2.y + t3.w * v3.y;
      acc[3][2] += t3.x * v0.z + t3.y * v1.z + t3.z * v2.z + t3.w * v3.z;
      acc[3][3] += t3.x * v0.w + t3.y * v1.w + t3.z * v2.w + t3.w * v3.w;
    }
  }

  float4 b2v = *(const float4*)(b2 + ct * 4);
#pragma unroll
  for (int nk = 0; nk < 4; ++nk) {
    float4 o;
    o.x = acc[nk][0] + b2v.x;
    o.y = acc[nk][1] + b2v.y;
    o.z = acc[nk][2] + b2v.z;
    o.w = acc[nk][3] + b2v.w;
    *(float4*)(out + (r0 + nt * 4 + nk) * CDIM + ct * 4) = o;
  }
}

extern "C" void kernel_launch(void* const* d_in, const int* in_sizes, int n_in,
                              void* d_out, int out_size, void* d_ws, size_t ws_size,
                              hipStream_t stream) {
  const float* x0 = (const float*)d_in[0];
  const int* ei = (const int*)d_in[1];
  const float* W1_0 = (const float*)d_in[2];
  const float* b1_0 = (const float*)d_in[3];
  const float* W2_0 = (const float*)d_in[4];
  const float* b2_0 = (const float*)d_in[5];
  const float* W1_1 = (const float*)d_in[6];
  const float* b1_1 = (const float*)d_in[7];
  const float* W2_1 = (const float*)d_in[8];
  const float* b2_1 = (const float*)d_in[9];
  float* out = (float*)d_out;
  float* h = (float*)d_ws;  // (B*N, C) fp32 = 51.2 MB scratch

  const int n4 = ROWS * CDIM / 4;                       // 3.2M float4
  const long long scatThreads = (long long)NB * NEDGES * 32;
  const int scatBlocks = (int)((scatThreads + MT - 1) / MT);  // 200000
  const int mlpBlocks = ROWS / NPB;                     // 3125

  // layer 0
  copy_f4<<<2048, MT, 0, stream>>>((const float4*)x0, (float4*)h, n4);
  scatter_add_k<<<scatBlocks, MT, 0, stream>>>(x0, ei, h);
  mlp_fused<<<mlpBlocks, MT, 0, stream>>>(h, W1_0, b1_0, W2_0, b2_0, out);
  // layer 1
  copy_f4<<<2048, MT, 0, stream>>>((const float4*)out, (float4*)h, n4);
  scatter_add_k<<<scatBlocks, MT, 0, stream>>>(out, ei, h);
  mlp_fused<<<mlpBlocks, MT, 0, stream>>>(h, W1_1, b1_1, W2_1, b2_1, out);
}

// Round 2
// 1390.354 us; speedup vs baseline: 4.6645x; 4.6645x over previous
//
#include <hip/hip_runtime.h>

#define CDIM 128
#define HDIM 512
#define NB 2
#define NNODES 50000
#define NEDGES 800000
#define ROWS (NB * NNODES)

#define NPB 32   // nodes per block in MLP
#define HC 64    // hidden chunk
#define MT 256   // threads per block

// ---------------- CSR build ----------------

__global__ void hist_k(const int* __restrict__ ei, int* __restrict__ counts) {
  int e = blockIdx.x * 256 + threadIdx.x;
  if (e < NEDGES) atomicAdd(&counts[ei[NEDGES + e]], 1);
}

// single-block exclusive scan of counts[N] -> offsets[N] (+ offsets[N]=E), cursor copy
__global__ __launch_bounds__(1024) void scan_k(const int* __restrict__ counts,
                                               int* __restrict__ offsets,
                                               int* __restrict__ cursor) {
  __shared__ int sm[1024];
  __shared__ int carry;
  if (threadIdx.x == 0) carry = 0;
  __syncthreads();
  for (int base = 0; base < NNODES; base += 1024) {
    int i = base + threadIdx.x;
    int v = (i < NNODES) ? counts[i] : 0;
    sm[threadIdx.x] = v;
    __syncthreads();
    for (int off = 1; off < 1024; off <<= 1) {
      int t = (threadIdx.x >= off) ? sm[threadIdx.x - off] : 0;
      __syncthreads();
      sm[threadIdx.x] += t;
      __syncthreads();
    }
    int excl = sm[threadIdx.x] - v;
    if (i < NNODES) {
      int o = carry + excl;
      offsets[i] = o;
      cursor[i] = o;
    }
    __syncthreads();
    if (threadIdx.x == 1023) carry += sm[1023];
    __syncthreads();
  }
  if (threadIdx.x == 0) offsets[NNODES] = NEDGES;
}

__global__ void fill_k(const int* __restrict__ ei, int* __restrict__ cursor,
                       int* __restrict__ col) {
  int e = blockIdx.x * 256 + threadIdx.x;
  if (e < NEDGES) {
    int d = ei[NEDGES + e];
    int p = atomicAdd(&cursor[d], 1);
    col[p] = ei[e];
  }
}

// ---------------- aggregation: h[b,n,:] = x[b,n,:] + sum_{e: dst=n} x[b,col[e],:]
__global__ __launch_bounds__(256) void agg_k(const float* __restrict__ x,
                                             const int* __restrict__ offs,
                                             const int* __restrict__ col,
                                             float* __restrict__ h) {
  int node = blockIdx.x * 8 + (threadIdx.x >> 5);
  int q = threadIdx.x & 31;
  int b = blockIdx.y;
  if (node >= NNODES) return;
  const float* xb = x + (size_t)b * NNODES * CDIM;
  float4 acc = *(const float4*)(xb + (size_t)node * CDIM + q * 4);
  int e0 = offs[node], e1 = offs[node + 1];
  for (int e = e0; e < e1; ++e) {
    int s = col[e];
    const float4 v = *(const float4*)(xb + (size_t)s * CDIM + q * 4);
    acc.x += v.x;
    acc.y += v.y;
    acc.z += v.z;
    acc.w += v.w;
  }
  *(float4*)(h + ((size_t)b * NNODES + node) * CDIM + q * 4) = acc;
}

// ---------------- fused MLP: out = relu(h @ W1 + b1) @ W2 + b2 (in-place safe)
__global__ __launch_bounds__(MT) void mlp_fused(
    const float* __restrict__ hin, const float* __restrict__ W1,
    const float* __restrict__ b1, const float* __restrict__ W2,
    const float* __restrict__ b2, float* __restrict__ out) {
  __shared__ float sh[NPB][CDIM + 4];
  __shared__ float st[NPB][HC + 4];
  __shared__ float wbuf[CDIM * (HC + 4)];

  const int tid = threadIdx.x;
  const size_t r0 = (size_t)blockIdx.x * NPB;

  for (int i = tid; i < NPB * (CDIM / 4); i += MT) {
    int n = i >> 5, c4 = i & 31;
    *(float4*)&sh[n][c4 * 4] = *(const float4*)(hin + (r0 + n) * CDIM + c4 * 4);
  }

  const int ct = tid & 31, nt = tid >> 5;
  const int jt = tid & 15, nt2 = tid >> 4;

  float acc[4][4] = {{0.f}};

  for (int chunk = 0; chunk < HDIM / HC; ++chunk) {
    const int j0 = chunk * HC;
    __syncthreads();
    for (int i = tid; i < CDIM * (HC / 4); i += MT) {
      int c = i >> 4, jq = i & 15;
      *(float4*)&wbuf[c * (HC + 4) + jq * 4] =
          *(const float4*)(W1 + (size_t)c * HDIM + j0 + jq * 4);
    }
    __syncthreads();

    float tacc[4][2] = {{0.f}};
#pragma unroll 4
    for (int c4 = 0; c4 < CDIM / 4; ++c4) {
      float4 h0 = *(const float4*)&sh[nt2 * 2 + 0][c4 * 4];
      float4 h1 = *(const float4*)&sh[nt2 * 2 + 1][c4 * 4];
      float4 w0 = *(const float4*)&wbuf[(c4 * 4 + 0) * (HC + 4) + jt * 4];
      float4 w1 = *(const float4*)&wbuf[(c4 * 4 + 1) * (HC + 4) + jt * 4];
      float4 w2 = *(const float4*)&wbuf[(c4 * 4 + 2) * (HC + 4) + jt * 4];
      float4 w3 = *(const float4*)&wbuf[(c4 * 4 + 3) * (HC + 4) + jt * 4];
      tacc[0][0] += h0.x * w0.x + h0.y * w1.x + h0.z * w2.x + h0.w * w3.x;
      tacc[1][0] += h0.x * w0.y + h0.y * w1.y + h0.z * w2.y + h0.w * w3.y;
      tacc[2][0] += h0.x * w0.z + h0.y * w1.z + h0.z * w2.z + h0.w * w3.z;
      tacc[3][0] += h0.x * w0.w + h0.y * w1.w + h0.z * w2.w + h0.w * w3.w;
      tacc[0][1] += h1.x * w0.x + h1.y * w1.x + h1.z * w2.x + h1.w * w3.x;
      tacc[1][1] += h1.x * w0.y + h1.y * w1.y + h1.z * w2.y + h1.w * w3.y;
      tacc[2][1] += h1.x * w0.z + h1.y * w1.z + h1.z * w2.z + h1.w * w3.z;
      tacc[3][1] += h1.x * w0.w + h1.y * w1.w + h1.z * w2.w + h1.w * w3.w;
    }
    {
      float4 b1v = *(const float4*)(b1 + j0 + jt * 4);
      float4 o0, o1;
      o0.x = fmaxf(tacc[0][0] + b1v.x, 0.f);
      o0.y = fmaxf(tacc[1][0] + b1v.y, 0.f);
      o0.z = fmaxf(tacc[2][0] + b1v.z, 0.f);
      o0.w = fmaxf(tacc[3][0] + b1v.w, 0.f);
      o1.x = fmaxf(tacc[0][1] + b1v.x, 0.f);
      o1.y = fmaxf(tacc[1][1] + b1v.y, 0.f);
      o1.z = fmaxf(tacc[2][1] + b1v.z, 0.f);
      o1.w = fmaxf(tacc[3][1] + b1v.w, 0.f);
      *(float4*)&st[nt2 * 2 + 0][jt * 4] = o0;
      *(float4*)&st[nt2 * 2 + 1][jt * 4] = o1;
    }
    __syncthreads();
    for (int i = tid; i < HC * (CDIM / 4); i += MT) {
      int j = i >> 5, cq = i & 31;
      *(float4*)&wbuf[j * (CDIM + 4) + cq * 4] =
          *(const float4*)(W2 + (size_t)(j0 + j) * CDIM + cq * 4);
    }
    __syncthreads();

#pragma unroll 4
    for (int j4 = 0; j4 < HC / 4; ++j4) {
      float4 t0 = *(const float4*)&st[nt * 4 + 0][j4 * 4];
      float4 t1 = *(const float4*)&st[nt * 4 + 1][j4 * 4];
      float4 t2 = *(const float4*)&st[nt * 4 + 2][j4 * 4];
      float4 t3 = *(const float4*)&st[nt * 4 + 3][j4 * 4];
      float4 v0 = *(const float4*)&wbuf[(j4 * 4 + 0) * (CDIM + 4) + ct * 4];
      float4 v1 = *(const float4*)&wbuf[(j4 * 4 + 1) * (CDIM + 4) + ct * 4];
      float4 v2 = *(const float4*)&wbuf[(j4 * 4 + 2) * (CDIM + 4) + ct * 4];
      float4 v3 = *(const float4*)&wbuf[(j4 * 4 + 3) * (CDIM + 4) + ct * 4];
      acc[0][0] += t0.x * v0.x + t0.y * v1.x + t0.z * v2.x + t0.w * v3.x;
      acc[0][1] += t0.x * v0.y + t0.y * v1.y + t0.z * v2.y + t0.w * v3.y;
      acc[0][2] += t0.x * v0.z + t0.y * v1.z + t0.z * v2.z + t0.w * v3.z;
      acc[0][3] += t0.x * v0.w + t0.y * v1.w + t0.z * v2.w + t0.w * v3.w;
      acc[1][0] += t1.x * v0.x + t1.y * v1.x + t1.z * v2.x + t1.w * v3.x;
      acc[1][1] += t1.x * v0.y + t1.y * v1.y + t1.z * v2.y + t1.w * v3.y;
      acc[1][2] += t1.x * v0.z + t1.y * v1.z + t1.z * v2.z + t1.w * v3.z;
      acc[1][3] += t1.x * v0.w + t1.y * v1.w + t1.z * v2.w + t1.w * v3.w;
      acc[2][0] += t2.x * v0.x + t2.y * v1.x + t2.z * v2.x + t2.w * v3.x;
      acc[2][1] += t2.x * v0.y + t2.y * v1.y + t2.z * v2.y + t2.w * v3.y;
      acc[2][2] += t2.x * v0.z + t2.y * v1.z + t2.z * v2.z + t2.w * v3.z;
      acc[2][3] += t2.x * v0.w + t2.y * v1.w + t2.z * v2.w + t2.w * v3.w;
      acc[3][0] += t3.x * v0.x + t3.y * v1.x + t3.z * v2.x + t3.w * v3.x;
      acc[3][1] += t3.x * v0.y + t3.y * v1.y + t3.z * v2.y + t3.w * v3.y;
      acc[3][2] += t3.x * v0.z + t3.y * v1.z + t3.z * v2.z + t3.w * v3.z;
      acc[3][3] += t3.x * v0.w + t3.y * v1.w + t3.z * v2.w + t3.w * v3.w;
    }
  }

  float4 b2v = *(const float4*)(b2 + ct * 4);
#pragma unroll
  for (int nk = 0; nk < 4; ++nk) {
    float4 o;
    o.x = acc[nk][0] + b2v.x;
    o.y = acc[nk][1] + b2v.y;
    o.z = acc[nk][2] + b2v.z;
    o.w = acc[nk][3] + b2v.w;
    *(float4*)(out + (r0 + nt * 4 + nk) * CDIM + ct * 4) = o;
  }
}

extern "C" void kernel_launch(void* const* d_in, const int* in_sizes, int n_in,
                              void* d_out, int out_size, void* d_ws, size_t ws_size,
                              hipStream_t stream) {
  const float* x0 = (const float*)d_in[0];
  const int* ei = (const int*)d_in[1];
  const float* W1_0 = (const float*)d_in[2];
  const float* b1_0 = (const float*)d_in[3];
  const float* W2_0 = (const float*)d_in[4];
  const float* b2_0 = (const float*)d_in[5];
  const float* W1_1 = (const float*)d_in[6];
  const float* b1_1 = (const float*)d_in[7];
  const float* W2_1 = (const float*)d_in[8];
  const float* b2_1 = (const float*)d_in[9];
  float* out = (float*)d_out;

  // workspace layout
  float* buf1 = (float*)d_ws;                         // ROWS*CDIM fp32 = 51.2 MB
  int* counts = (int*)(buf1 + (size_t)ROWS * CDIM);   // N
  int* offsets = counts + NNODES;                     // N+1
  int* cursor = offsets + NNODES + 1;                 // N
  int* col = cursor + NNODES;                         // E

  const int eBlocks = (NEDGES + 255) / 256;           // 3125
  const int aggBlocks = (NNODES + 7) / 8;             // 6250
  const int mlpBlocks = ROWS / NPB;                   // 3125

  // CSR build (once per launch, shared by both layers/batches)
  hipMemsetAsync(counts, 0, NNODES * sizeof(int), stream);
  hist_k<<<eBlocks, 256, 0, stream>>>(ei, counts);
  scan_k<<<1, 1024, 0, stream>>>(counts, offsets, cursor);
  fill_k<<<eBlocks, 256, 0, stream>>>(ei, cursor, col);

  // layer 0: agg(x0) -> buf1 ; MLP in-place buf1
  agg_k<<<dim3(aggBlocks, NB), 256, 0, stream>>>(x0, offsets, col, buf1);
  mlp_fused<<<mlpBlocks, MT, 0, stream>>>(buf1, W1_0, b1_0, W2_0, b2_0, buf1);
  // layer 1: agg(buf1) -> out ; MLP in-place out
  agg_k<<<dim3(aggBlocks, NB), 256, 0, stream>>>(buf1, offsets, col, out);
  mlp_fused<<<mlpBlocks, MT, 0, stream>>>(out, W1_1, b1_1, W2_1, b2_1, out);
}

// Round 3
// 810.180 us; speedup vs baseline: 8.0048x; 1.7161x over previous
//
#include <hip/hip_runtime.h>

#define CDIM 128
#define HDIM 512
#define NB 2
#define NNODES 50000
#define NEDGES 800000
#define ROWS (NB * NNODES)

typedef short short8 __attribute__((ext_vector_type(8)));
typedef __bf16 bf16x8 __attribute__((ext_vector_type(8)));
typedef float f32x4 __attribute__((ext_vector_type(4)));

__device__ __forceinline__ unsigned short f2bf_rn(float x) {
  unsigned u = __float_as_uint(x);
  unsigned r = u + 0x7fffu + ((u >> 16) & 1u);
  return (unsigned short)(r >> 16);
}
__device__ __forceinline__ void split2(float x, unsigned short& h, unsigned short& l) {
  h = f2bf_rn(x);
  float hf = __uint_as_float((unsigned)h << 16);
  l = f2bf_rn(x - hf);
}
__device__ __forceinline__ f32x4 mfma_bf16(short8 a, short8 b, f32x4 c) {
  return __builtin_amdgcn_mfma_f32_16x16x32_bf16(
      __builtin_bit_cast(bf16x8, a), __builtin_bit_cast(bf16x8, b), c, 0, 0, 0);
}

// ---------------- CSR build ----------------
__global__ void hist_k(const int* __restrict__ ei, int* __restrict__ counts) {
  int e = blockIdx.x * 256 + threadIdx.x;
  if (e < NEDGES) atomicAdd(&counts[ei[NEDGES + e]], 1);
}

__global__ __launch_bounds__(1024) void scan_k(const int* __restrict__ counts,
                                               int* __restrict__ offsets,
                                               int* __restrict__ cursor) {
  __shared__ int sm[1024];
  __shared__ int carry;
  if (threadIdx.x == 0) carry = 0;
  __syncthreads();
  for (int base = 0; base < NNODES; base += 1024) {
    int i = base + threadIdx.x;
    int v = (i < NNODES) ? counts[i] : 0;
    sm[threadIdx.x] = v;
    __syncthreads();
    for (int off = 1; off < 1024; off <<= 1) {
      int t = (threadIdx.x >= off) ? sm[threadIdx.x - off] : 0;
      __syncthreads();
      sm[threadIdx.x] += t;
      __syncthreads();
    }
    int excl = sm[threadIdx.x] - v;
    if (i < NNODES) {
      int o = carry + excl;
      offsets[i] = o;
      cursor[i] = o;
    }
    __syncthreads();
    if (threadIdx.x == 1023) carry += sm[1023];
    __syncthreads();
  }
  if (threadIdx.x == 0) offsets[NNODES] = NEDGES;
}

__global__ void fill_k(const int* __restrict__ ei, int* __restrict__ cursor,
                       int* __restrict__ col) {
  int e = blockIdx.x * 256 + threadIdx.x;
  if (e < NEDGES) {
    int d = ei[NEDGES + e];
    int p = atomicAdd(&cursor[d], 1);
    col[p] = ei[e];
  }
}

// ---------------- aggregation ----------------
__global__ __launch_bounds__(256) void agg_k(const float* __restrict__ x,
                                             const int* __restrict__ offs,
                                             const int* __restrict__ col,
                                             float* __restrict__ h) {
  int node = blockIdx.x * 8 + (threadIdx.x >> 5);
  int q = threadIdx.x & 31;
  int b = blockIdx.y;
  if (node >= NNODES) return;
  const float* xb = x + (size_t)b * NNODES * CDIM;
  float4 acc = *(const float4*)(xb + (size_t)node * CDIM + q * 4);
  int e0 = offs[node], e1 = offs[node + 1];
  for (int e = e0; e < e1; ++e) {
    int s = col[e];
    const float4 v = *(const float4*)(xb + (size_t)s * CDIM + q * 4);
    acc.x += v.x;
    acc.y += v.y;
    acc.z += v.z;
    acc.w += v.w;
  }
  *(float4*)(h + ((size_t)b * NNODES + node) * CDIM + q * 4) = acc;
}

// ---------------- weight pre-pack: fp32 W[K][N] -> hi/lo bf16 B-fragments ----
// frag f = nt*(K/32) + kt; lane l holds W[kt*32 + (l>>4)*8 + i][nt*16 + (l&15)]
__global__ void pack_w(const float* __restrict__ W, int K, int N,
                       unsigned short* __restrict__ hi, unsigned short* __restrict__ lo) {
  int tid = blockIdx.x * 256 + threadIdx.x;
  int total = (K >> 5) * (N >> 4) * 64;
  if (tid >= total) return;
  int l = tid & 63;
  int f = tid >> 6;
  int KT = K >> 5;
  int nt = f / KT, kt = f - nt * KT;
  int k0 = kt * 32 + (l >> 4) * 8;
  int n = nt * 16 + (l & 15);
#pragma unroll
  for (int i = 0; i < 8; ++i) {
    float x = W[(size_t)(k0 + i) * N + n];
    unsigned short h_, l_;
    split2(x, h_, l_);
    hi[(size_t)tid * 8 + i] = h_;
    lo[(size_t)tid * 8 + i] = l_;
  }
}

// ---------------- fused MLP via split-bf16 MFMA ----------------
// block = 128 rows, 4 waves x 32 rows; chunked over H in 8 chunks of 64
__global__ __launch_bounds__(256, 2) void mlp_mfma(
    const float* __restrict__ hin,
    const unsigned short* __restrict__ w1h, const unsigned short* __restrict__ w1l,
    const float* __restrict__ b1,
    const unsigned short* __restrict__ w2h, const unsigned short* __restrict__ w2l,
    const float* __restrict__ b2, float* __restrict__ out) {
  __shared__ unsigned t_lds[4][32 * 64];  // per-wave t chunk, (hi<<16)|lo, swizzled

  const int lane = threadIdx.x & 63;
  const int wid = threadIdx.x >> 6;
  const int l15 = lane & 15, lg = lane >> 4;
  const long long r0 = (long long)blockIdx.x * 128 + wid * 32;

  const short8* w1hp = (const short8*)w1h;
  const short8* w1lp = (const short8*)w1l;
  const short8* w2hp = (const short8*)w2h;
  const short8* w2lp = (const short8*)w2l;

  // load + split A (this wave's 32 h-rows, K=128)
  short8 Ah[2][4], Al[2][4];
#pragma unroll
  for (int rt = 0; rt < 2; ++rt) {
    long long row = r0 + rt * 16 + l15;
    if (row >= ROWS) row = ROWS - 1;
    const float* hp = hin + row * CDIM + lg * 8;
#pragma unroll
    for (int ks = 0; ks < 4; ++ks) {
      float4 a0 = *(const float4*)(hp + ks * 32);
      float4 a1 = *(const float4*)(hp + ks * 32 + 4);
      float av[8] = {a0.x, a0.y, a0.z, a0.w, a1.x, a1.y, a1.z, a1.w};
#pragma unroll
      for (int i = 0; i < 8; ++i) {
        unsigned short h_, l_;
        split2(av[i], h_, l_);
        Ah[rt][ks][i] = (short)h_;
        Al[rt][ks][i] = (short)l_;
      }
    }
  }

  f32x4 acc[2][8];
#pragma unroll
  for (int rt = 0; rt < 2; ++rt)
#pragma unroll
    for (int ct = 0; ct < 8; ++ct) acc[rt][ct] = (f32x4){0.f, 0.f, 0.f, 0.f};

  unsigned* tl = &t_lds[wid][0];

  for (int chunk = 0; chunk < 8; ++chunk) {
    // GEMM1: t[32 x 64] = A[32 x 128] * W1[:, chunk*64 .. +64]
    f32x4 tacc[2][4];
#pragma unroll
    for (int rt = 0; rt < 2; ++rt)
#pragma unroll
      for (int jt = 0; jt < 4; ++jt) tacc[rt][jt] = (f32x4){0.f, 0.f, 0.f, 0.f};

#pragma unroll
    for (int ks = 0; ks < 4; ++ks) {
#pragma unroll
      for (int jt = 0; jt < 4; ++jt) {
        int f = (chunk * 4 + jt) * 4 + ks;
        short8 bh = w1hp[(size_t)f * 64 + lane];
        short8 bl = w1lp[(size_t)f * 64 + lane];
#pragma unroll
        for (int rt = 0; rt < 2; ++rt) {
          tacc[rt][jt] = mfma_bf16(Ah[rt][ks], bh, tacc[rt][jt]);
          tacc[rt][jt] = mfma_bf16(Ah[rt][ks], bl, tacc[rt][jt]);
          tacc[rt][jt] = mfma_bf16(Al[rt][ks], bh, tacc[rt][jt]);
        }
      }
    }

    // bias + relu + split -> LDS (hi|lo packed dword, XOR swizzle)
#pragma unroll
    for (int jt = 0; jt < 4; ++jt) {
      float b1v = b1[chunk * 64 + jt * 16 + l15];
#pragma unroll
      for (int rt = 0; rt < 2; ++rt) {
#pragma unroll
        for (int r = 0; r < 4; ++r) {
          float v = fmaxf(tacc[rt][jt][r] + b1v, 0.f);
          unsigned short h_, l_;
          split2(v, h_, l_);
          int rl = rt * 16 + lg * 4 + r;
          int c = jt * 16 + l15;
          tl[rl * 64 + (c ^ ((rl & 7) << 3))] = ((unsigned)h_ << 16) | (unsigned)l_;
        }
      }
    }

    // GEMM2 partial: acc[32 x 128] += relu_t[32 x 64] * W2[chunk*64.. , :]
#pragma unroll
    for (int ks2 = 0; ks2 < 2; ++ks2) {
      short8 a2h[2], a2l[2];
#pragma unroll
      for (int rt = 0; rt < 2; ++rt) {
        int rl = rt * 16 + l15;
        int sc = (ks2 * 32 + lg * 8) ^ ((rl & 7) << 3);
        const uint4* p = (const uint4*)&tl[rl * 64 + sc];
        uint4 d0 = p[0], d1 = p[1];
        unsigned dw[8] = {d0.x, d0.y, d0.z, d0.w, d1.x, d1.y, d1.z, d1.w};
#pragma unroll
        for (int i = 0; i < 8; ++i) {
          a2h[rt][i] = (short)(dw[i] >> 16);
          a2l[rt][i] = (short)(dw[i] & 0xffffu);
        }
      }
#pragma unroll
      for (int ct = 0; ct < 8; ++ct) {
        int f = ct * 16 + chunk * 2 + ks2;
        short8 bh = w2hp[(size_t)f * 64 + lane];
        short8 bl = w2lp[(size_t)f * 64 + lane];
#pragma unroll
        for (int rt = 0; rt < 2; ++rt) {
          acc[rt][ct] = mfma_bf16(a2h[rt], bh, acc[rt][ct]);
          acc[rt][ct] = mfma_bf16(a2h[rt], bl, acc[rt][ct]);
          acc[rt][ct] = mfma_bf16(a2l[rt], bh, acc[rt][ct]);
        }
      }
    }
  }

  // epilogue: + b2, store
#pragma unroll
  for (int ct = 0; ct < 8; ++ct) {
    float b2v = b2[ct * 16 + l15];
#pragma unroll
    for (int rt = 0; rt < 2; ++rt) {
#pragma unroll
      for (int r = 0; r < 4; ++r) {
        long long row = r0 + rt * 16 + lg * 4 + r;
        if (row < ROWS) out[row * CDIM + ct * 16 + l15] = acc[rt][ct][r] + b2v;
      }
    }
  }
}

extern "C" void kernel_launch(void* const* d_in, const int* in_sizes, int n_in,
                              void* d_out, int out_size, void* d_ws, size_t ws_size,
                              hipStream_t stream) {
  const float* x0 = (const float*)d_in[0];
  const int* ei = (const int*)d_in[1];
  const float* W1_0 = (const float*)d_in[2];
  const float* b1_0 = (const float*)d_in[3];
  const float* W2_0 = (const float*)d_in[4];
  const float* b2_0 = (const float*)d_in[5];
  const float* W1_1 = (const float*)d_in[6];
  const float* b1_1 = (const float*)d_in[7];
  const float* W2_1 = (const float*)d_in[8];
  const float* b2_1 = (const float*)d_in[9];
  float* out = (float*)d_out;

  // workspace layout
  float* buf1 = (float*)d_ws;                          // ROWS*CDIM fp32 (51.2 MB)
  int* counts = (int*)(buf1 + (size_t)ROWS * CDIM);    // N
  int* offsets = counts + NNODES;                      // N+1
  int* cursor = offsets + NNODES + 1;                  // N
  int* col = cursor + NNODES;                          // E
  unsigned short* wp = (unsigned short*)(col + NEDGES);
  const size_t WSZ = (size_t)CDIM * HDIM;  // 65536 elements per matrix
  unsigned short* w1h0 = wp;
  unsigned short* w1l0 = w1h0 + WSZ;
  unsigned short* w2h0 = w1l0 + WSZ;
  unsigned short* w2l0 = w2h0 + WSZ;
  unsigned short* w1h1 = w2l0 + WSZ;
  unsigned short* w1l1 = w1h1 + WSZ;
  unsigned short* w2h1 = w1l1 + WSZ;
  unsigned short* w2l1 = w2h1 + WSZ;

  const int eBlocks = (NEDGES + 255) / 256;
  const int aggBlocks = (NNODES + 7) / 8;
  const int mlpBlocks = (ROWS + 127) / 128;  // 782

  // CSR build
  hipMemsetAsync(counts, 0, NNODES * sizeof(int), stream);
  hist_k<<<eBlocks, 256, 0, stream>>>(ei, counts);
  scan_k<<<1, 1024, 0, stream>>>(counts, offsets, cursor);
  fill_k<<<eBlocks, 256, 0, stream>>>(ei, cursor, col);

  // weight pre-pack (once per launch)
  pack_w<<<32, 256, 0, stream>>>(W1_0, CDIM, HDIM, w1h0, w1l0);
  pack_w<<<32, 256, 0, stream>>>(W2_0, HDIM, CDIM, w2h0, w2l0);
  pack_w<<<32, 256, 0, stream>>>(W1_1, CDIM, HDIM, w1h1, w1l1);
  pack_w<<<32, 256, 0, stream>>>(W2_1, HDIM, CDIM, w2h1, w2l1);

  // layer 0
  agg_k<<<dim3(aggBlocks, NB), 256, 0, stream>>>(x0, offsets, col, buf1);
  mlp_mfma<<<mlpBlocks, 256, 0, stream>>>(buf1, w1h0, w1l0, b1_0, w2h0, w2l0, b2_0, buf1);
  // layer 1
  agg_k<<<dim3(aggBlocks, NB), 256, 0, stream>>>(buf1, offsets, col, out);
  mlp_mfma<<<mlpBlocks, 256, 0, stream>>>(out, w1h1, w1l1, b1_1, w2h1, w2l1, b2_1, out);
}

// Round 4
// 646.870 us; speedup vs baseline: 10.0258x; 1.2525x over previous
//
#include <hip/hip_runtime.h>

#define CDIM 128
#define HDIM 512
#define NB 2
#define NNODES 50000
#define NEDGES 800000
#define ROWS (NB * NNODES)

typedef _Float16 half8 __attribute__((ext_vector_type(8)));
typedef float f32x4 __attribute__((ext_vector_type(4)));

__device__ __forceinline__ f32x4 mfma_f16(half8 a, half8 b, f32x4 c) {
  return __builtin_amdgcn_mfma_f32_16x16x32_f16(a, b, c, 0, 0, 0);
}

// ---------------- CSR build ----------------
__global__ void hist_k(const int* __restrict__ ei, int* __restrict__ counts) {
  int e = blockIdx.x * 256 + threadIdx.x;
  if (e < NEDGES) atomicAdd(&counts[ei[NEDGES + e]], 1);
}

__global__ __launch_bounds__(1024) void scan_k(const int* __restrict__ counts,
                                               int* __restrict__ offsets,
                                               int* __restrict__ cursor) {
  __shared__ int sm[1024];
  __shared__ int carry;
  if (threadIdx.x == 0) carry = 0;
  __syncthreads();
  for (int base = 0; base < NNODES; base += 1024) {
    int i = base + threadIdx.x;
    int v = (i < NNODES) ? counts[i] : 0;
    sm[threadIdx.x] = v;
    __syncthreads();
    for (int off = 1; off < 1024; off <<= 1) {
      int t = (threadIdx.x >= off) ? sm[threadIdx.x - off] : 0;
      __syncthreads();
      sm[threadIdx.x] += t;
      __syncthreads();
    }
    int excl = sm[threadIdx.x] - v;
    if (i < NNODES) {
      int o = carry + excl;
      offsets[i] = o;
      cursor[i] = o;
    }
    __syncthreads();
    if (threadIdx.x == 1023) carry += sm[1023];
    __syncthreads();
  }
  if (threadIdx.x == 0) offsets[NNODES] = NEDGES;
}

__global__ void fill_k(const int* __restrict__ ei, int* __restrict__ cursor,
                       int* __restrict__ col) {
  int e = blockIdx.x * 256 + threadIdx.x;
  if (e < NEDGES) {
    int d = ei[NEDGES + e];
    int p = atomicAdd(&cursor[d], 1);
    col[p] = ei[e];
  }
}

// ---------------- aggregation ----------------
__global__ __launch_bounds__(256) void agg_k(const float* __restrict__ x,
                                             const int* __restrict__ offs,
                                             const int* __restrict__ col,
                                             float* __restrict__ h) {
  int node = blockIdx.x * 8 + (threadIdx.x >> 5);
  int q = threadIdx.x & 31;
  int b = blockIdx.y;
  if (node >= NNODES) return;
  const float* xb = x + (size_t)b * NNODES * CDIM;
  float4 acc = *(const float4*)(xb + (size_t)node * CDIM + q * 4);
  int e0 = offs[node], e1 = offs[node + 1];
  for (int e = e0; e < e1; ++e) {
    int s = col[e];
    const float4 v = *(const float4*)(xb + (size_t)s * CDIM + q * 4);
    acc.x += v.x;
    acc.y += v.y;
    acc.z += v.z;
    acc.w += v.w;
  }
  *(float4*)(h + ((size_t)b * NNODES + node) * CDIM + q * 4) = acc;
}

// ---------------- weight pre-pack: fp32 W[K][N] -> fp16 B-fragments ----------
// frag f = nt*(K/32) + kt; lane l holds W[kt*32 + (l>>4)*8 + i][nt*16 + (l&15)]
__global__ void pack16(const float* __restrict__ W, int K, int N,
                       unsigned short* __restrict__ dst) {
  int tid = blockIdx.x * 256 + threadIdx.x;
  int total = (K >> 5) * (N >> 4) * 64;
  if (tid >= total) return;
  int l = tid & 63;
  int f = tid >> 6;
  int KT = K >> 5;
  int nt = f / KT, kt = f - nt * KT;
  int k0 = kt * 32 + (l >> 4) * 8;
  int n = nt * 16 + (l & 15);
#pragma unroll
  for (int i = 0; i < 8; ++i) {
    _Float16 v = (_Float16)W[(size_t)(k0 + i) * N + n];
    dst[(size_t)tid * 8 + i] = __builtin_bit_cast(unsigned short, v);
  }
}

// ---------------- fused MLP via fp16 MFMA ----------------
// block = 128 threads = 2 waves x 32 rows; H chunked 8 x 64; no barriers.
__global__ __launch_bounds__(128) void mlp_mfma(
    const float* __restrict__ hin,
    const unsigned short* __restrict__ w1p, const float* __restrict__ b1,
    const unsigned short* __restrict__ w2p, const float* __restrict__ b2,
    float* __restrict__ out) {
  __shared__ unsigned t_lds[2][32 * 64];  // per-wave t chunk (fp32 bits), swizzled

  const int lane = threadIdx.x & 63;
  const int wid = threadIdx.x >> 6;
  const int l15 = lane & 15, lg = lane >> 4;
  const long long r0 = (long long)blockIdx.x * 64 + wid * 32;

  const half8* w1f = (const half8*)w1p;
  const half8* w2f = (const half8*)w2p;

  // load A (this wave's 32 h-rows, K=128) as fp16 frags
  half8 A[2][4];
#pragma unroll
  for (int rt = 0; rt < 2; ++rt) {
    long long row = r0 + rt * 16 + l15;
    if (row >= ROWS) row = ROWS - 1;
    const float* hp = hin + row * CDIM + lg * 8;
#pragma unroll
    for (int ks = 0; ks < 4; ++ks) {
      float4 a0 = *(const float4*)(hp + ks * 32);
      float4 a1 = *(const float4*)(hp + ks * 32 + 4);
      A[rt][ks][0] = (_Float16)a0.x;
      A[rt][ks][1] = (_Float16)a0.y;
      A[rt][ks][2] = (_Float16)a0.z;
      A[rt][ks][3] = (_Float16)a0.w;
      A[rt][ks][4] = (_Float16)a1.x;
      A[rt][ks][5] = (_Float16)a1.y;
      A[rt][ks][6] = (_Float16)a1.z;
      A[rt][ks][7] = (_Float16)a1.w;
    }
  }

  f32x4 acc[2][8];
#pragma unroll
  for (int rt = 0; rt < 2; ++rt)
#pragma unroll
    for (int ct = 0; ct < 8; ++ct) acc[rt][ct] = (f32x4){0.f, 0.f, 0.f, 0.f};

  unsigned* tl = &t_lds[wid][0];

  for (int chunk = 0; chunk < 8; ++chunk) {
    // GEMM1: t[32 x 64] = A[32 x 128] * W1[:, chunk*64 .. +64]
    f32x4 tacc[2][4];
#pragma unroll
    for (int rt = 0; rt < 2; ++rt)
#pragma unroll
      for (int jt = 0; jt < 4; ++jt) tacc[rt][jt] = (f32x4){0.f, 0.f, 0.f, 0.f};

#pragma unroll
    for (int ks = 0; ks < 4; ++ks) {
#pragma unroll
      for (int jt = 0; jt < 4; ++jt) {
        int f = (chunk * 4 + jt) * 4 + ks;
        half8 b = w1f[(size_t)f * 64 + lane];
#pragma unroll
        for (int rt = 0; rt < 2; ++rt) tacc[rt][jt] = mfma_f16(A[rt][ks], b, tacc[rt][jt]);
      }
    }

    // bias + relu -> LDS (fp32 bits, XOR swizzle)
#pragma unroll
    for (int jt = 0; jt < 4; ++jt) {
      float b1v = b1[chunk * 64 + jt * 16 + l15];
#pragma unroll
      for (int rt = 0; rt < 2; ++rt) {
#pragma unroll
        for (int r = 0; r < 4; ++r) {
          float v = fmaxf(tacc[rt][jt][r] + b1v, 0.f);
          int rl = rt * 16 + lg * 4 + r;
          int c = jt * 16 + l15;
          tl[rl * 64 + (c ^ ((rl & 7) << 3))] = __float_as_uint(v);
        }
      }
    }

    // GEMM2 partial: acc[32 x 128] += relu_t[32 x 64] * W2[chunk*64.. , :]
#pragma unroll
    for (int ks2 = 0; ks2 < 2; ++ks2) {
      half8 a2[2];
#pragma unroll
      for (int rt = 0; rt < 2; ++rt) {
        int rl = rt * 16 + l15;
        int sc = (ks2 * 32 + lg * 8) ^ ((rl & 7) << 3);
        const uint4* p = (const uint4*)&tl[rl * 64 + sc];
        uint4 d0 = p[0], d1 = p[1];
        a2[rt][0] = (_Float16)__uint_as_float(d0.x);
        a2[rt][1] = (_Float16)__uint_as_float(d0.y);
        a2[rt][2] = (_Float16)__uint_as_float(d0.z);
        a2[rt][3] = (_Float16)__uint_as_float(d0.w);
        a2[rt][4] = (_Float16)__uint_as_float(d1.x);
        a2[rt][5] = (_Float16)__uint_as_float(d1.y);
        a2[rt][6] = (_Float16)__uint_as_float(d1.z);
        a2[rt][7] = (_Float16)__uint_as_float(d1.w);
      }
#pragma unroll
      for (int ct = 0; ct < 8; ++ct) {
        int f = ct * 16 + chunk * 2 + ks2;
        half8 b = w2f[(size_t)f * 64 + lane];
#pragma unroll
        for (int rt = 0; rt < 2; ++rt) acc[rt][ct] = mfma_f16(a2[rt], b, acc[rt][ct]);
      }
    }
  }

  // epilogue: + b2, store
#pragma unroll
  for (int ct = 0; ct < 8; ++ct) {
    float b2v = b2[ct * 16 + l15];
#pragma unroll
    for (int rt = 0; rt < 2; ++rt) {
#pragma unroll
      for (int r = 0; r < 4; ++r) {
        long long row = r0 + rt * 16 + lg * 4 + r;
        if (row < ROWS) out[row * CDIM + ct * 16 + l15] = acc[rt][ct][r] + b2v;
      }
    }
  }
}

extern "C" void kernel_launch(void* const* d_in, const int* in_sizes, int n_in,
                              void* d_out, int out_size, void* d_ws, size_t ws_size,
                              hipStream_t stream) {
  const float* x0 = (const float*)d_in[0];
  const int* ei = (const int*)d_in[1];
  const float* W1_0 = (const float*)d_in[2];
  const float* b1_0 = (const float*)d_in[3];
  const float* W2_0 = (const float*)d_in[4];
  const float* b2_0 = (const float*)d_in[5];
  const float* W1_1 = (const float*)d_in[6];
  const float* b1_1 = (const float*)d_in[7];
  const float* W2_1 = (const float*)d_in[8];
  const float* b2_1 = (const float*)d_in[9];
  float* out = (float*)d_out;

  // workspace layout
  float* buf1 = (float*)d_ws;                          // ROWS*CDIM fp32 (51.2 MB)
  int* counts = (int*)(buf1 + (size_t)ROWS * CDIM);    // N
  int* offsets = counts + NNODES;                      // N+1
  int* cursor = offsets + NNODES + 1;                  // N
  int* col = cursor + NNODES;                          // E
  unsigned short* wp = (unsigned short*)(col + NEDGES);
  const size_t WSZ = (size_t)CDIM * HDIM;  // 65536 elements per matrix
  unsigned short* w1f0 = wp;
  unsigned short* w2f0 = w1f0 + WSZ;
  unsigned short* w1f1 = w2f0 + WSZ;
  unsigned short* w2f1 = w1f1 + WSZ;

  const int eBlocks = (NEDGES + 255) / 256;
  const int aggBlocks = (NNODES + 7) / 8;
  const int mlpBlocks = (ROWS + 63) / 64;  // 1563

  // CSR build
  hipMemsetAsync(counts, 0, NNODES * sizeof(int), stream);
  hist_k<<<eBlocks, 256, 0, stream>>>(ei, counts);
  scan_k<<<1, 1024, 0, stream>>>(counts, offsets, cursor);
  fill_k<<<eBlocks, 256, 0, stream>>>(ei, cursor, col);

  // weight pre-pack (once per launch)
  pack16<<<32, 256, 0, stream>>>(W1_0, CDIM, HDIM, w1f0);
  pack16<<<32, 256, 0, stream>>>(W2_0, HDIM, CDIM, w2f0);
  pack16<<<32, 256, 0, stream>>>(W1_1, CDIM, HDIM, w1f1);
  pack16<<<32, 256, 0, stream>>>(W2_1, HDIM, CDIM, w2f1);

  // layer 0
  agg_k<<<dim3(aggBlocks, NB), 256, 0, stream>>>(x0, offsets, col, buf1);
  mlp_mfma<<<mlpBlocks, 128, 0, stream>>>(buf1, w1f0, b1_0, w2f0, b2_0, buf1);
  // layer 1
  agg_k<<<dim3(aggBlocks, NB), 256, 0, stream>>>(buf1, offsets, col, out);
  mlp_mfma<<<mlpBlocks, 128, 0, stream>>>(out, w1f1, b1_1, w2f1, b2_1, out);
}

// Round 5
// 549.507 us; speedup vs baseline: 11.8021x; 1.1772x over previous
//
#include <hip/hip_runtime.h>

#define CDIM 128
#define HDIM 512
#define NB 2
#define NNODES 50000
#define NEDGES 800000
#define ROWS (NB * NNODES)

typedef _Float16 half8 __attribute__((ext_vector_type(8)));
typedef _Float16 half4 __attribute__((ext_vector_type(4)));
typedef float f32x4 __attribute__((ext_vector_type(4)));

__device__ __forceinline__ f32x4 mfma_f16(half8 a, half8 b, f32x4 c) {
  return __builtin_amdgcn_mfma_f32_16x16x32_f16(a, b, c, 0, 0, 0);
}

// ---------------- CSR build ----------------
__global__ void hist_k(const int* __restrict__ ei, int* __restrict__ counts) {
  int e = blockIdx.x * 256 + threadIdx.x;
  if (e < NEDGES) atomicAdd(&counts[ei[NEDGES + e]], 1);
}

__global__ __launch_bounds__(1024) void scan_k(const int* __restrict__ counts,
                                               int* __restrict__ offsets,
                                               int* __restrict__ cursor) {
  __shared__ int sm[1024];
  __shared__ int carry;
  if (threadIdx.x == 0) carry = 0;
  __syncthreads();
  for (int base = 0; base < NNODES; base += 1024) {
    int i = base + threadIdx.x;
    int v = (i < NNODES) ? counts[i] : 0;
    sm[threadIdx.x] = v;
    __syncthreads();
    for (int off = 1; off < 1024; off <<= 1) {
      int t = (threadIdx.x >= off) ? sm[threadIdx.x - off] : 0;
      __syncthreads();
      sm[threadIdx.x] += t;
      __syncthreads();
    }
    int excl = sm[threadIdx.x] - v;
    if (i < NNODES) {
      int o = carry + excl;
      offsets[i] = o;
      cursor[i] = o;
    }
    __syncthreads();
    if (threadIdx.x == 1023) carry += sm[1023];
    __syncthreads();
  }
  if (threadIdx.x == 0) offsets[NNODES] = NEDGES;
}

__global__ void fill_k(const int* __restrict__ ei, int* __restrict__ cursor,
                       int* __restrict__ col) {
  int e = blockIdx.x * 256 + threadIdx.x;
  if (e < NEDGES) {
    int d = ei[NEDGES + e];
    int p = atomicAdd(&cursor[d], 1);
    col[p] = ei[e];
  }
}

// ---------------- fp32 -> fp16 feature convert ----------------
__global__ void cvt16_k(const float* __restrict__ s, _Float16* __restrict__ d, int n8) {
  int i = blockIdx.x * 256 + threadIdx.x;
  int str = gridDim.x * 256;
  for (; i < n8; i += str) {
    float4 f0 = *(const float4*)(s + (size_t)i * 8);
    float4 f1 = *(const float4*)(s + (size_t)i * 8 + 4);
    half8 o;
    o[0] = (_Float16)f0.x; o[1] = (_Float16)f0.y;
    o[2] = (_Float16)f0.z; o[3] = (_Float16)f0.w;
    o[4] = (_Float16)f1.x; o[5] = (_Float16)f1.y;
    o[6] = (_Float16)f1.z; o[7] = (_Float16)f1.w;
    *(half8*)(d + (size_t)i * 8) = o;
  }
}

// ---------------- aggregation (fp16 in/out, fp32 accumulate) ----------------
__global__ __launch_bounds__(256) void agg16_k(const _Float16* __restrict__ x,
                                               const int* __restrict__ offs,
                                               const int* __restrict__ col,
                                               _Float16* __restrict__ h) {
  int node = blockIdx.x * 8 + (threadIdx.x >> 5);
  int q = threadIdx.x & 31;  // 4 halfs (8 B) per lane
  int b = blockIdx.y;
  if (node >= NNODES) return;
  const _Float16* xb = x + (size_t)b * NNODES * CDIM;
  half4 self = *(const half4*)(xb + (size_t)node * CDIM + q * 4);
  float a0 = (float)self[0], a1 = (float)self[1], a2 = (float)self[2], a3 = (float)self[3];
  int e0 = offs[node], e1 = offs[node + 1];
  int e = e0;
  for (; e + 1 < e1; e += 2) {
    int s0 = col[e], s1 = col[e + 1];
    half4 v0 = *(const half4*)(xb + (size_t)s0 * CDIM + q * 4);
    half4 v1 = *(const half4*)(xb + (size_t)s1 * CDIM + q * 4);
    a0 += (float)v0[0] + (float)v1[0];
    a1 += (float)v0[1] + (float)v1[1];
    a2 += (float)v0[2] + (float)v1[2];
    a3 += (float)v0[3] + (float)v1[3];
  }
  if (e < e1) {
    int s0 = col[e];
    half4 v0 = *(const half4*)(xb + (size_t)s0 * CDIM + q * 4);
    a0 += (float)v0[0];
    a1 += (float)v0[1];
    a2 += (float)v0[2];
    a3 += (float)v0[3];
  }
  half4 r;
  r[0] = (_Float16)a0; r[1] = (_Float16)a1;
  r[2] = (_Float16)a2; r[3] = (_Float16)a3;
  *(half4*)(h + ((size_t)b * NNODES + node) * CDIM + q * 4) = r;
}

// ---------------- weight pre-pack: fp32 W[K][N] -> fp16 B-fragments ----------
// frag f = nt*(K/32) + kt; lane l holds W[kt*32 + (l>>4)*8 + i][nt*16 + (l&15)]
__global__ void pack16(const float* __restrict__ W, int K, int N,
                       unsigned short* __restrict__ dst) {
  int tid = blockIdx.x * 256 + threadIdx.x;
  int total = (K >> 5) * (N >> 4) * 64;
  if (tid >= total) return;
  int l = tid & 63;
  int f = tid >> 6;
  int KT = K >> 5;
  int nt = f / KT, kt = f - nt * KT;
  int k0 = kt * 32 + (l >> 4) * 8;
  int n = nt * 16 + (l & 15);
#pragma unroll
  for (int i = 0; i < 8; ++i) {
    _Float16 v = (_Float16)W[(size_t)(k0 + i) * N + n];
    dst[(size_t)tid * 8 + i] = __builtin_bit_cast(unsigned short, v);
  }
}

// ---------------- fused MLP via fp16 MFMA ----------------
// block = 128 threads = 2 waves x 32 rows; H chunked 8 x 64; no barriers.
template <typename OT>
__global__ __launch_bounds__(128) void mlp_mfma(
    const _Float16* __restrict__ hin,
    const unsigned short* __restrict__ w1p, const float* __restrict__ b1,
    const unsigned short* __restrict__ w2p, const float* __restrict__ b2,
    OT* __restrict__ out) {
  __shared__ unsigned t_lds[2][32 * 64];  // per-wave t chunk (fp32 bits), swizzled

  const int lane = threadIdx.x & 63;
  const int wid = threadIdx.x >> 6;
  const int l15 = lane & 15, lg = lane >> 4;
  const long long r0 = (long long)blockIdx.x * 64 + wid * 32;

  const half8* w1f = (const half8*)w1p;
  const half8* w2f = (const half8*)w2p;

  // load A (this wave's 32 h-rows, K=128): direct fp16 fragment loads
  half8 A[2][4];
#pragma unroll
  for (int rt = 0; rt < 2; ++rt) {
    long long row = r0 + rt * 16 + l15;
    if (row >= ROWS) row = ROWS - 1;
    const _Float16* hp = hin + row * CDIM + lg * 8;
#pragma unroll
    for (int ks = 0; ks < 4; ++ks) A[rt][ks] = *(const half8*)(hp + ks * 32);
  }

  f32x4 acc[2][8];
#pragma unroll
  for (int rt = 0; rt < 2; ++rt)
#pragma unroll
    for (int ct = 0; ct < 8; ++ct) acc[rt][ct] = (f32x4){0.f, 0.f, 0.f, 0.f};

  unsigned* tl = &t_lds[wid][0];

  for (int chunk = 0; chunk < 8; ++chunk) {
    // GEMM1: t[32 x 64] = A[32 x 128] * W1[:, chunk*64 .. +64]
    f32x4 tacc[2][4];
#pragma unroll
    for (int rt = 0; rt < 2; ++rt)
#pragma unroll
      for (int jt = 0; jt < 4; ++jt) tacc[rt][jt] = (f32x4){0.f, 0.f, 0.f, 0.f};

#pragma unroll
    for (int ks = 0; ks < 4; ++ks) {
#pragma unroll
      for (int jt = 0; jt < 4; ++jt) {
        int f = (chunk * 4 + jt) * 4 + ks;
        half8 b = w1f[(size_t)f * 64 + lane];
#pragma unroll
        for (int rt = 0; rt < 2; ++rt) tacc[rt][jt] = mfma_f16(A[rt][ks], b, tacc[rt][jt]);
      }
    }

    // bias + relu -> LDS (fp32 bits, XOR swizzle)
#pragma unroll
    for (int jt = 0; jt < 4; ++jt) {
      float b1v = b1[chunk * 64 + jt * 16 + l15];
#pragma unroll
      for (int rt = 0; rt < 2; ++rt) {
#pragma unroll
        for (int r = 0; r < 4; ++r) {
          float v = fmaxf(tacc[rt][jt][r] + b1v, 0.f);
          int rl = rt * 16 + lg * 4 + r;
          int c = jt * 16 + l15;
          tl[rl * 64 + (c ^ ((rl & 7) << 3))] = __float_as_uint(v);
        }
      }
    }

    // GEMM2 partial: acc[32 x 128] += relu_t[32 x 64] * W2[chunk*64.. , :]
#pragma unroll
    for (int ks2 = 0; ks2 < 2; ++ks2) {
      half8 a2[2];
#pragma unroll
      for (int rt = 0; rt < 2; ++rt) {
        int rl = rt * 16 + l15;
        int sc = (ks2 * 32 + lg * 8) ^ ((rl & 7) << 3);
        const uint4* p = (const uint4*)&tl[rl * 64 + sc];
        uint4 d0 = p[0], d1 = p[1];
        a2[rt][0] = (_Float16)__uint_as_float(d0.x);
        a2[rt][1] = (_Float16)__uint_as_float(d0.y);
        a2[rt][2] = (_Float16)__uint_as_float(d0.z);
        a2[rt][3] = (_Float16)__uint_as_float(d0.w);
        a2[rt][4] = (_Float16)__uint_as_float(d1.x);
        a2[rt][5] = (_Float16)__uint_as_float(d1.y);
        a2[rt][6] = (_Float16)__uint_as_float(d1.z);
        a2[rt][7] = (_Float16)__uint_as_float(d1.w);
      }
#pragma unroll
      for (int ct = 0; ct < 8; ++ct) {
        int f = ct * 16 + chunk * 2 + ks2;
        half8 b = w2f[(size_t)f * 64 + lane];
#pragma unroll
        for (int rt = 0; rt < 2; ++rt) acc[rt][ct] = mfma_f16(a2[rt], b, acc[rt][ct]);
      }
    }
  }

  // epilogue: + b2, store
#pragma unroll
  for (int ct = 0; ct < 8; ++ct) {
    float b2v = b2[ct * 16 + l15];
#pragma unroll
    for (int rt = 0; rt < 2; ++rt) {
#pragma unroll
      for (int r = 0; r < 4; ++r) {
        long long row = r0 + rt * 16 + lg * 4 + r;
        if (row < ROWS) out[row * CDIM + ct * 16 + l15] = (OT)(acc[rt][ct][r] + b2v);
      }
    }
  }
}

extern "C" void kernel_launch(void* const* d_in, const int* in_sizes, int n_in,
                              void* d_out, int out_size, void* d_ws, size_t ws_size,
                              hipStream_t stream) {
  const float* x0 = (const float*)d_in[0];
  const int* ei = (const int*)d_in[1];
  const float* W1_0 = (const float*)d_in[2];
  const float* b1_0 = (const float*)d_in[3];
  const float* W2_0 = (const float*)d_in[4];
  const float* b2_0 = (const float*)d_in[5];
  const float* W1_1 = (const float*)d_in[6];
  const float* b1_1 = (const float*)d_in[7];
  const float* W2_1 = (const float*)d_in[8];
  const float* b2_1 = (const float*)d_in[9];
  float* out = (float*)d_out;

  // workspace layout (fp16 feature buffers)
  _Float16* xh = (_Float16*)d_ws;                      // ROWS*CDIM fp16 (25.6 MB)
  _Float16* hh = xh + (size_t)ROWS * CDIM;             // ROWS*CDIM fp16 (25.6 MB)
  int* counts = (int*)(hh + (size_t)ROWS * CDIM);      // N
  int* offsets = counts + NNODES;                      // N+1
  int* cursor = offsets + NNODES + 1;                  // N
  int* col = cursor + NNODES;                          // E
  unsigned short* wp = (unsigned short*)(col + NEDGES);
  const size_t WSZ = (size_t)CDIM * HDIM;
  unsigned short* w1f0 = wp;
  unsigned short* w2f0 = w1f0 + WSZ;
  unsigned short* w1f1 = w2f0 + WSZ;
  unsigned short* w2f1 = w1f1 + WSZ;

  const int eBlocks = (NEDGES + 255) / 256;
  const int aggBlocks = (NNODES + 7) / 8;
  const int mlpBlocks = (ROWS + 63) / 64;  // 1563
  const int n8 = ROWS * CDIM / 8;

  // CSR build
  hipMemsetAsync(counts, 0, NNODES * sizeof(int), stream);
  hist_k<<<eBlocks, 256, 0, stream>>>(ei, counts);
  scan_k<<<1, 1024, 0, stream>>>(counts, offsets, cursor);
  fill_k<<<eBlocks, 256, 0, stream>>>(ei, cursor, col);

  // weight pre-pack (once per launch)
  pack16<<<32, 256, 0, stream>>>(W1_0, CDIM, HDIM, w1f0);
  pack16<<<32, 256, 0, stream>>>(W2_0, HDIM, CDIM, w2f0);
  pack16<<<32, 256, 0, stream>>>(W1_1, CDIM, HDIM, w1f1);
  pack16<<<32, 256, 0, stream>>>(W2_1, HDIM, CDIM, w2f1);

  // x -> fp16
  cvt16_k<<<2048, 256, 0, stream>>>(x0, xh, n8);

  // layer 0: agg(xh) -> hh ; mlp(hh) -> xh (fp16 y1, reuse buffer)
  agg16_k<<<dim3(aggBlocks, NB), 256, 0, stream>>>(xh, offsets, col, hh);
  mlp_mfma<_Float16><<<mlpBlocks, 128, 0, stream>>>(hh, w1f0, b1_0, w2f0, b2_0, xh);
  // layer 1: agg(xh=y1) -> hh ; mlp(hh) -> out (fp32)
  agg16_k<<<dim3(aggBlocks, NB), 256, 0, stream>>>(xh, offsets, col, hh);
  mlp_mfma<float><<<mlpBlocks, 128, 0, stream>>>(hh, w1f1, b1_1, w2f1, b2_1, out);
}

// Round 6
// 411.596 us; speedup vs baseline: 15.7566x; 1.3351x over previous
//
#include <hip/hip_runtime.h>

#define CDIM 128
#define HDIM 512
#define NB 2
#define NNODES 50000
#define NEDGES 800000
#define ROWS (NB * NNODES)

typedef _Float16 half8 __attribute__((ext_vector_type(8)));
typedef _Float16 half4 __attribute__((ext_vector_type(4)));
typedef float f32x4 __attribute__((ext_vector_type(4)));

__device__ __forceinline__ f32x4 mfma_f16(half8 a, half8 b, f32x4 c) {
  return __builtin_amdgcn_mfma_f32_16x16x32_f16(a, b, c, 0, 0, 0);
}

#define GLOAD_LDS16(g, l)                                                      \
  __builtin_amdgcn_global_load_lds(                                            \
      (const __attribute__((address_space(1))) void*)(g),                      \
      (__attribute__((address_space(3))) void*)(l), 16, 0, 0)

// ---------------- CSR build ----------------
__global__ void hist_k(const int* __restrict__ ei, int* __restrict__ counts) {
  int e = blockIdx.x * 256 + threadIdx.x;
  if (e < NEDGES) atomicAdd(&counts[ei[NEDGES + e]], 1);
}

__global__ __launch_bounds__(1024) void scan_k(const int* __restrict__ counts,
                                               int* __restrict__ offsets,
                                               int* __restrict__ cursor) {
  __shared__ int sm[1024];
  __shared__ int carry;
  if (threadIdx.x == 0) carry = 0;
  __syncthreads();
  for (int base = 0; base < NNODES; base += 4096) {
    int i0 = base + threadIdx.x * 4;
    int v[4];
#pragma unroll
    for (int k = 0; k < 4; ++k) v[k] = (i0 + k < NNODES) ? counts[i0 + k] : 0;
    int s = v[0] + v[1] + v[2] + v[3];
    sm[threadIdx.x] = s;
    __syncthreads();
    for (int off = 1; off < 1024; off <<= 1) {
      int t = (threadIdx.x >= off) ? sm[threadIdx.x - off] : 0;
      __syncthreads();
      sm[threadIdx.x] += t;
      __syncthreads();
    }
    int run = carry + sm[threadIdx.x] - s;
#pragma unroll
    for (int k = 0; k < 4; ++k) {
      if (i0 + k < NNODES) {
        offsets[i0 + k] = run;
        cursor[i0 + k] = run;
      }
      run += v[k];
    }
    __syncthreads();
    if (threadIdx.x == 1023) carry += sm[1023];
    __syncthreads();
  }
  if (threadIdx.x == 0) offsets[NNODES] = NEDGES;
}

__global__ void fill_k(const int* __restrict__ ei, int* __restrict__ cursor,
                       int* __restrict__ col) {
  int e = blockIdx.x * 256 + threadIdx.x;
  if (e < NEDGES) {
    int d = ei[NEDGES + e];
    int p = atomicAdd(&cursor[d], 1);
    col[p] = ei[e];
  }
}

// ---------------- fp32 -> fp16 feature convert ----------------
__global__ void cvt16_k(const float* __restrict__ s, _Float16* __restrict__ d, int n8) {
  int i = blockIdx.x * 256 + threadIdx.x;
  int str = gridDim.x * 256;
  for (; i < n8; i += str) {
    float4 f0 = *(const float4*)(s + (size_t)i * 8);
    float4 f1 = *(const float4*)(s + (size_t)i * 8 + 4);
    half8 o;
    o[0] = (_Float16)f0.x; o[1] = (_Float16)f0.y;
    o[2] = (_Float16)f0.z; o[3] = (_Float16)f0.w;
    o[4] = (_Float16)f1.x; o[5] = (_Float16)f1.y;
    o[6] = (_Float16)f1.z; o[7] = (_Float16)f1.w;
    *(half8*)(d + (size_t)i * 8) = o;
  }
}

// ---------------- aggregation (fp16 in/out, fp32 accumulate) ----------------
__global__ __launch_bounds__(256) void agg16_k(const _Float16* __restrict__ x,
                                               const int* __restrict__ offs,
                                               const int* __restrict__ col,
                                               _Float16* __restrict__ h) {
  int node = blockIdx.x * 8 + (threadIdx.x >> 5);
  int q = threadIdx.x & 31;
  int b = blockIdx.y;
  if (node >= NNODES) return;
  const _Float16* xb = x + (size_t)b * NNODES * CDIM;
  half4 self = *(const half4*)(xb + (size_t)node * CDIM + q * 4);
  float a0 = (float)self[0], a1 = (float)self[1], a2 = (float)self[2], a3 = (float)self[3];
  int e0 = offs[node], e1 = offs[node + 1];
  int e = e0;
  for (; e + 1 < e1; e += 2) {
    int s0 = col[e], s1 = col[e + 1];
    half4 v0 = *(const half4*)(xb + (size_t)s0 * CDIM + q * 4);
    half4 v1 = *(const half4*)(xb + (size_t)s1 * CDIM + q * 4);
    a0 += (float)v0[0] + (float)v1[0];
    a1 += (float)v0[1] + (float)v1[1];
    a2 += (float)v0[2] + (float)v1[2];
    a3 += (float)v0[3] + (float)v1[3];
  }
  if (e < e1) {
    int s0 = col[e];
    half4 v0 = *(const half4*)(xb + (size_t)s0 * CDIM + q * 4);
    a0 += (float)v0[0];
    a1 += (float)v0[1];
    a2 += (float)v0[2];
    a3 += (float)v0[3];
  }
  half4 r;
  r[0] = (_Float16)a0; r[1] = (_Float16)a1;
  r[2] = (_Float16)a2; r[3] = (_Float16)a3;
  *(half4*)(h + ((size_t)b * NNODES + node) * CDIM + q * 4) = r;
}

// ---------------- weight pre-pack into per-chunk merged fragment layout ------
// dst halfs: [chunk c:16][8 KB W1c | 8 KB W2c]  (chunk stride 8192 halfs)
// W1c frag g = jt*4+ks: lane l holds W1[ks*32+(l>>4)*8+i][c*32+jt*16+(l&15)]
// W2c frag g = ct:      lane l holds W2[c*32+(l>>4)*8+i][ct*16+(l&15)]
__global__ void pack_mlp(const float* __restrict__ W1, const float* __restrict__ W2,
                         _Float16* __restrict__ dst) {
  int tid = blockIdx.x * 256 + threadIdx.x;  // 0..16383
  if (tid >= 16384) return;
  int l = tid & 63;
  int g = (tid >> 6) & 7;
  int c = (tid >> 9) & 15;
  int isW2 = tid >> 13;
  int lg = l >> 4, l15 = l & 15;
  _Float16* o;
  if (!isW2) {
    int jt = g >> 2, ks = g & 3;
    int k0 = ks * 32 + lg * 8;
    int n = c * 32 + jt * 16 + l15;
    o = dst + (size_t)c * 8192 + g * 512 + l * 8;
#pragma unroll
    for (int i = 0; i < 8; ++i) o[i] = (_Float16)W1[(size_t)(k0 + i) * HDIM + n];
  } else {
    int k0 = c * 32 + lg * 8;
    int n = g * 16 + l15;
    o = dst + (size_t)c * 8192 + 4096 + g * 512 + l * 8;
#pragma unroll
    for (int i = 0; i < 8; ++i) o[i] = (_Float16)W2[(size_t)(k0 + i) * CDIM + n];
  }
}

// ---------------- fused MLP: LDS-shared W, double-buffered staging ----------
// 256 threads = 4 waves x 32 rows; 16 hidden-chunks of 32.
template <typename OT>
__global__ __launch_bounds__(256, 4) void mlp_v3(
    const _Float16* __restrict__ hin, const _Float16* __restrict__ wpk,
    const float* __restrict__ b1, const float* __restrict__ b2,
    OT* __restrict__ out) {
  __shared__ alignas(16) _Float16 wbuf[2][8192];  // 32 KB (W1c 4096 | W2c 4096 halfs)
  __shared__ alignas(16) _Float16 tbuf[4][32 * 32];  // 8 KB, per-wave, swizzled

  const int tidx = threadIdx.x;
  const int lane = tidx & 63;
  const int wid = tidx >> 6;
  const int l15 = lane & 15, lg = lane >> 4;
  const long long r0 = (long long)blockIdx.x * 128 + wid * 32;

  // A fragments: this wave's 32 rows, K=128 (resident all kernel)
  half8 A[2][4];
#pragma unroll
  for (int rt = 0; rt < 2; ++rt) {
    long long row = r0 + rt * 16 + l15;
    if (row >= ROWS) row = ROWS - 1;
    const _Float16* hp = hin + row * CDIM + lg * 8;
#pragma unroll
    for (int ks = 0; ks < 4; ++ks) A[rt][ks] = *(const half8*)(hp + ks * 32);
  }

  // prologue: stage chunk 0
  {
    const _Float16* src = wpk;
#pragma unroll
    for (int q = 0; q < 4; ++q) {
      int s = wid * 4 + q;
      GLOAD_LDS16(src + s * 512 + lane * 8, &wbuf[0][s * 512]);
    }
  }
  __syncthreads();

  f32x4 acc[2][8];
#pragma unroll
  for (int rt = 0; rt < 2; ++rt)
#pragma unroll
    for (int ct = 0; ct < 8; ++ct) acc[rt][ct] = (f32x4){0.f, 0.f, 0.f, 0.f};

  _Float16* tw = &tbuf[wid][0];

  for (int c = 0; c < 16; ++c) {
    const int cur = c & 1;
    if (c + 1 < 16) {  // stage next chunk into the other buffer
      const _Float16* src = wpk + (size_t)(c + 1) * 8192;
#pragma unroll
      for (int q = 0; q < 4; ++q) {
        int s = wid * 4 + q;
        GLOAD_LDS16(src + s * 512 + lane * 8, &wbuf[cur ^ 1][s * 512]);
      }
    }
    const _Float16* w1c = &wbuf[cur][0];
    const _Float16* w2c = &wbuf[cur][4096];

    // GEMM1: t[32n][32j] = A * W1c ; bias+relu ; fp16 -> tbuf (XOR swizzled)
#pragma unroll
    for (int jt = 0; jt < 2; ++jt) {
      f32x4 t0 = (f32x4){0.f, 0.f, 0.f, 0.f};
      f32x4 t1 = (f32x4){0.f, 0.f, 0.f, 0.f};
#pragma unroll
      for (int ks = 0; ks < 4; ++ks) {
        half8 b = *(const half8*)(w1c + (jt * 4 + ks) * 512 + lane * 8);
        t0 = mfma_f16(A[0][ks], b, t0);
        t1 = mfma_f16(A[1][ks], b, t1);
      }
      float bb = b1[c * 32 + jt * 16 + l15];
      int j = jt * 16 + l15;
#pragma unroll
      for (int r = 0; r < 4; ++r) {
        int n0 = lg * 4 + r;
        tw[n0 * 32 + (j ^ (((n0 >> 2) & 3) << 3))] = (_Float16)fmaxf(t0[r] + bb, 0.f);
        int n1 = 16 + lg * 4 + r;
        tw[n1 * 32 + (j ^ (((n1 >> 2) & 3) << 3))] = (_Float16)fmaxf(t1[r] + bb, 0.f);
      }
    }

    // GEMM2: acc += t * W2c
    half8 ta0, ta1;
    {
      int n = l15;
      ta0 = *(const half8*)(tw + n * 32 + ((lg * 8) ^ (((n >> 2) & 3) << 3)));
      n = 16 + l15;
      ta1 = *(const half8*)(tw + n * 32 + ((lg * 8) ^ (((n >> 2) & 3) << 3)));
    }
#pragma unroll
    for (int ct = 0; ct < 8; ++ct) {
      half8 b = *(const half8*)(w2c + ct * 512 + lane * 8);
      acc[0][ct] = mfma_f16(ta0, b, acc[0][ct]);
      acc[1][ct] = mfma_f16(ta1, b, acc[1][ct]);
    }
    __syncthreads();  // stage(c+1) drained; wbuf[cur] free for stage(c+2)
  }

  // epilogue: + b2, store
#pragma unroll
  for (int ct = 0; ct < 8; ++ct) {
    float b2v = b2[ct * 16 + l15];
#pragma unroll
    for (int rt = 0; rt < 2; ++rt) {
#pragma unroll
      for (int r = 0; r < 4; ++r) {
        long long row = r0 + rt * 16 + lg * 4 + r;
        if (row < ROWS) out[row * CDIM + ct * 16 + l15] = (OT)(acc[rt][ct][r] + b2v);
      }
    }
  }
}

extern "C" void kernel_launch(void* const* d_in, const int* in_sizes, int n_in,
                              void* d_out, int out_size, void* d_ws, size_t ws_size,
                              hipStream_t stream) {
  const float* x0 = (const float*)d_in[0];
  const int* ei = (const int*)d_in[1];
  const float* W1_0 = (const float*)d_in[2];
  const float* b1_0 = (const float*)d_in[3];
  const float* W2_0 = (const float*)d_in[4];
  const float* b2_0 = (const float*)d_in[5];
  const float* W1_1 = (const float*)d_in[6];
  const float* b1_1 = (const float*)d_in[7];
  const float* W2_1 = (const float*)d_in[8];
  const float* b2_1 = (const float*)d_in[9];
  float* out = (float*)d_out;

  // workspace layout (16B-aligned segments first)
  _Float16* xh = (_Float16*)d_ws;                  // ROWS*CDIM (25.6 MB)
  _Float16* hh = xh + (size_t)ROWS * CDIM;         // ROWS*CDIM (25.6 MB)
  _Float16* wpk0 = hh + (size_t)ROWS * CDIM;       // 131072 halfs (256 KB)
  _Float16* wpk1 = wpk0 + 131072;                  // 131072 halfs
  int* counts = (int*)(wpk1 + 131072);             // N
  int* offsets = counts + NNODES;                  // N+1
  int* cursor = offsets + NNODES + 1;              // N
  int* col = cursor + NNODES;                      // E

  const int eBlocks = (NEDGES + 255) / 256;
  const int aggBlocks = (NNODES + 7) / 8;
  const int mlpBlocks = (ROWS + 127) / 128;  // 782
  const int n8 = ROWS * CDIM / 8;

  // CSR build
  hipMemsetAsync(counts, 0, NNODES * sizeof(int), stream);
  hist_k<<<eBlocks, 256, 0, stream>>>(ei, counts);
  scan_k<<<1, 1024, 0, stream>>>(counts, offsets, cursor);
  fill_k<<<eBlocks, 256, 0, stream>>>(ei, cursor, col);

  // weight pre-pack (once per launch)
  pack_mlp<<<64, 256, 0, stream>>>(W1_0, W2_0, wpk0);
  pack_mlp<<<64, 256, 0, stream>>>(W1_1, W2_1, wpk1);

  // x -> fp16
  cvt16_k<<<2048, 256, 0, stream>>>(x0, xh, n8);

  // layer 0: agg(xh) -> hh ; mlp(hh) -> xh (fp16 y1)
  agg16_k<<<dim3(aggBlocks, NB), 256, 0, stream>>>(xh, offsets, col, hh);
  mlp_v3<_Float16><<<mlpBlocks, 256, 0, stream>>>(hh, wpk0, b1_0, b2_0, xh);
  // layer 1: agg(xh=y1) -> hh ; mlp(hh) -> out (fp32)
  agg16_k<<<dim3(aggBlocks, NB), 256, 0, stream>>>(xh, offsets, col, hh);
  mlp_v3<float><<<mlpBlocks, 256, 0, stream>>>(hh, wpk1, b1_1, b2_1, out);
}

// Round 7
// 367.641 us; speedup vs baseline: 17.6405x; 1.1196x over previous
//
#include <hip/hip_runtime.h>

#define CDIM 128
#define HDIM 512
#define NB 2
#define NNODES 50000
#define NEDGES 800000
#define ROWS (NB * NNODES)

typedef _Float16 half8 __attribute__((ext_vector_type(8)));
typedef _Float16 half4 __attribute__((ext_vector_type(4)));
typedef float f32x4 __attribute__((ext_vector_type(4)));

__device__ __forceinline__ f32x4 mfma_f16(half8 a, half8 b, f32x4 c) {
  return __builtin_amdgcn_mfma_f32_16x16x32_f16(a, b, c, 0, 0, 0);
}

#define GLOAD_LDS16(g, l)                                                      \
  __builtin_amdgcn_global_load_lds(                                            \
      (const __attribute__((address_space(1))) void*)(g),                      \
      (__attribute__((address_space(3))) void*)(l), 16, 0, 0)

// ---------------- CSR build ----------------
__global__ void hist_k(const int* __restrict__ ei, int* __restrict__ counts) {
  int e = blockIdx.x * 256 + threadIdx.x;
  if (e < NEDGES) atomicAdd(&counts[ei[NEDGES + e]], 1);
}

__global__ __launch_bounds__(1024) void scan_k(const int* __restrict__ counts,
                                               int* __restrict__ offsets,
                                               int* __restrict__ cursor) {
  __shared__ int sm[1024];
  __shared__ int carry;
  if (threadIdx.x == 0) carry = 0;
  __syncthreads();
  for (int base = 0; base < NNODES; base += 4096) {
    int i0 = base + threadIdx.x * 4;
    int v[4];
#pragma unroll
    for (int k = 0; k < 4; ++k) v[k] = (i0 + k < NNODES) ? counts[i0 + k] : 0;
    int s = v[0] + v[1] + v[2] + v[3];
    sm[threadIdx.x] = s;
    __syncthreads();
    for (int off = 1; off < 1024; off <<= 1) {
      int t = (threadIdx.x >= off) ? sm[threadIdx.x - off] : 0;
      __syncthreads();
      sm[threadIdx.x] += t;
      __syncthreads();
    }
    int run = carry + sm[threadIdx.x] - s;
#pragma unroll
    for (int k = 0; k < 4; ++k) {
      if (i0 + k < NNODES) {
        offsets[i0 + k] = run;
        cursor[i0 + k] = run;
      }
      run += v[k];
    }
    __syncthreads();
    if (threadIdx.x == 1023) carry += sm[1023];
    __syncthreads();
  }
  if (threadIdx.x == 0) offsets[NNODES] = NEDGES;
}

__global__ void fill_k(const int* __restrict__ ei, int* __restrict__ cursor,
                       int* __restrict__ col) {
  int e = blockIdx.x * 256 + threadIdx.x;
  if (e < NEDGES) {
    int d = ei[NEDGES + e];
    int p = atomicAdd(&cursor[d], 1);
    col[p] = ei[e];
  }
}

// ---- fp32 [b][n][c] -> fp16 batch-interleaved [n][b][c] ----
__global__ void cvt16i_k(const float* __restrict__ s, _Float16* __restrict__ d) {
  const int PB = NNODES * CDIM;
  int i = blockIdx.x * 256 + threadIdx.x;
  int str = gridDim.x * 256;
  for (; i < ROWS * (CDIM / 8); i += str) {
    size_t flat = (size_t)i * 8;
    int b = (int)(flat / PB);
    size_t r = flat - (size_t)b * PB;
    int n = (int)(r >> 7);
    int c0 = (int)(r & 127);
    float4 f0 = *(const float4*)(s + flat);
    float4 f1 = *(const float4*)(s + flat + 4);
    half8 o;
    o[0] = (_Float16)f0.x; o[1] = (_Float16)f0.y;
    o[2] = (_Float16)f0.z; o[3] = (_Float16)f0.w;
    o[4] = (_Float16)f1.x; o[5] = (_Float16)f1.y;
    o[6] = (_Float16)f1.z; o[7] = (_Float16)f1.w;
    *(half8*)(d + ((size_t)n * 2 + b) * CDIM + c0) = o;
  }
}

// ---- aggregation on interleaved layout: one wave per node, both batches ----
// row-pair = 512 B; lane owns 8 B (half4). col[e] is wave-uniform -> scalar.
__global__ __launch_bounds__(256) void aggi_k(const _Float16* __restrict__ x,
                                              const int* __restrict__ offs,
                                              const int* __restrict__ col,
                                              _Float16* __restrict__ h) {
  int node = blockIdx.x * 4 + (threadIdx.x >> 6);
  int lane = threadIdx.x & 63;
  if (node >= NNODES) return;
  const half4* xp = (const half4*)x;  // 64 half4 per node-pair
  half4 self = xp[(size_t)node * 64 + lane];
  float a0 = (float)self[0], a1 = (float)self[1], a2 = (float)self[2], a3 = (float)self[3];
  int e0 = offs[node], e1 = offs[node + 1];
  int e = e0;
  for (; e + 3 < e1; e += 4) {
    int s0 = col[e], s1 = col[e + 1], s2 = col[e + 2], s3 = col[e + 3];
    half4 v0 = xp[(size_t)s0 * 64 + lane];
    half4 v1 = xp[(size_t)s1 * 64 + lane];
    half4 v2 = xp[(size_t)s2 * 64 + lane];
    half4 v3 = xp[(size_t)s3 * 64 + lane];
    a0 += (float)v0[0] + (float)v1[0] + (float)v2[0] + (float)v3[0];
    a1 += (float)v0[1] + (float)v1[1] + (float)v2[1] + (float)v3[1];
    a2 += (float)v0[2] + (float)v1[2] + (float)v2[2] + (float)v3[2];
    a3 += (float)v0[3] + (float)v1[3] + (float)v2[3] + (float)v3[3];
  }
  for (; e < e1; ++e) {
    int s0 = col[e];
    half4 v0 = xp[(size_t)s0 * 64 + lane];
    a0 += (float)v0[0];
    a1 += (float)v0[1];
    a2 += (float)v0[2];
    a3 += (float)v0[3];
  }
  half4 r;
  r[0] = (_Float16)a0; r[1] = (_Float16)a1;
  r[2] = (_Float16)a2; r[3] = (_Float16)a3;
  ((half4*)h)[(size_t)node * 64 + lane] = r;
}

// ---------------- weight pre-pack into per-chunk merged fragment layout ------
__global__ void pack_mlp(const float* __restrict__ W1, const float* __restrict__ W2,
                         _Float16* __restrict__ dst) {
  int tid = blockIdx.x * 256 + threadIdx.x;  // 0..16383
  if (tid >= 16384) return;
  int l = tid & 63;
  int g = (tid >> 6) & 7;
  int c = (tid >> 9) & 15;
  int isW2 = tid >> 13;
  int lg = l >> 4, l15 = l & 15;
  _Float16* o;
  if (!isW2) {
    int jt = g >> 2, ks = g & 3;
    int k0 = ks * 32 + lg * 8;
    int n = c * 32 + jt * 16 + l15;
    o = dst + (size_t)c * 8192 + g * 512 + l * 8;
#pragma unroll
    for (int i = 0; i < 8; ++i) o[i] = (_Float16)W1[(size_t)(k0 + i) * HDIM + n];
  } else {
    int k0 = c * 32 + lg * 8;
    int n = g * 16 + l15;
    o = dst + (size_t)c * 8192 + 4096 + g * 512 + l * 8;
#pragma unroll
    for (int i = 0; i < 8; ++i) o[i] = (_Float16)W2[(size_t)(k0 + i) * CDIM + n];
  }
}

// ---------------- fused MLP: LDS-shared W, double-buffered staging ----------
// rows are interleaved (g = n*2+b). REMAP=true writes [b][n][c] fp32 output.
template <typename OT, bool REMAP>
__global__ __launch_bounds__(256, 4) void mlp_v3(
    const _Float16* __restrict__ hin, const _Float16* __restrict__ wpk,
    const float* __restrict__ b1, const float* __restrict__ b2,
    OT* __restrict__ out) {
  __shared__ alignas(16) _Float16 wbuf[2][8192];
  __shared__ alignas(16) _Float16 tbuf[4][32 * 32];

  const int tidx = threadIdx.x;
  const int lane = tidx & 63;
  const int wid = tidx >> 6;
  const int l15 = lane & 15, lg = lane >> 4;
  const long long r0 = (long long)blockIdx.x * 128 + wid * 32;

  half8 A[2][4];
#pragma unroll
  for (int rt = 0; rt < 2; ++rt) {
    long long row = r0 + rt * 16 + l15;
    if (row >= ROWS) row = ROWS - 1;
    const _Float16* hp = hin + row * CDIM + lg * 8;
#pragma unroll
    for (int ks = 0; ks < 4; ++ks) A[rt][ks] = *(const half8*)(hp + ks * 32);
  }

  {
    const _Float16* src = wpk;
#pragma unroll
    for (int q = 0; q < 4; ++q) {
      int s = wid * 4 + q;
      GLOAD_LDS16(src + s * 512 + lane * 8, &wbuf[0][s * 512]);
    }
  }
  __syncthreads();

  f32x4 acc[2][8];
#pragma unroll
  for (int rt = 0; rt < 2; ++rt)
#pragma unroll
    for (int ct = 0; ct < 8; ++ct) acc[rt][ct] = (f32x4){0.f, 0.f, 0.f, 0.f};

  _Float16* tw = &tbuf[wid][0];

  for (int c = 0; c < 16; ++c) {
    const int cur = c & 1;
    if (c + 1 < 16) {
      const _Float16* src = wpk + (size_t)(c + 1) * 8192;
#pragma unroll
      for (int q = 0; q < 4; ++q) {
        int s = wid * 4 + q;
        GLOAD_LDS16(src + s * 512 + lane * 8, &wbuf[cur ^ 1][s * 512]);
      }
    }
    const _Float16* w1c = &wbuf[cur][0];
    const _Float16* w2c = &wbuf[cur][4096];

#pragma unroll
    for (int jt = 0; jt < 2; ++jt) {
      f32x4 t0 = (f32x4){0.f, 0.f, 0.f, 0.f};
      f32x4 t1 = (f32x4){0.f, 0.f, 0.f, 0.f};
#pragma unroll
      for (int ks = 0; ks < 4; ++ks) {
        half8 b = *(const half8*)(w1c + (jt * 4 + ks) * 512 + lane * 8);
        t0 = mfma_f16(A[0][ks], b, t0);
        t1 = mfma_f16(A[1][ks], b, t1);
      }
      float bb = b1[c * 32 + jt * 16 + l15];
      int j = jt * 16 + l15;
#pragma unroll
      for (int r = 0; r < 4; ++r) {
        int n0 = lg * 4 + r;
        tw[n0 * 32 + (j ^ (((n0 >> 2) & 3) << 3))] = (_Float16)fmaxf(t0[r] + bb, 0.f);
        int n1 = 16 + lg * 4 + r;
        tw[n1 * 32 + (j ^ (((n1 >> 2) & 3) << 3))] = (_Float16)fmaxf(t1[r] + bb, 0.f);
      }
    }

    half8 ta0, ta1;
    {
      int n = l15;
      ta0 = *(const half8*)(tw + n * 32 + ((lg * 8) ^ (((n >> 2) & 3) << 3)));
      n = 16 + l15;
      ta1 = *(const half8*)(tw + n * 32 + ((lg * 8) ^ (((n >> 2) & 3) << 3)));
    }
#pragma unroll
    for (int ct = 0; ct < 8; ++ct) {
      half8 b = *(const half8*)(w2c + ct * 512 + lane * 8);
      acc[0][ct] = mfma_f16(ta0, b, acc[0][ct]);
      acc[1][ct] = mfma_f16(ta1, b, acc[1][ct]);
    }
    __syncthreads();
  }

#pragma unroll
  for (int ct = 0; ct < 8; ++ct) {
    float b2v = b2[ct * 16 + l15];
#pragma unroll
    for (int rt = 0; rt < 2; ++rt) {
#pragma unroll
      for (int r = 0; r < 4; ++r) {
        long long g = r0 + rt * 16 + lg * 4 + r;
        if (g < ROWS) {
          size_t off;
          if (REMAP) {
            // interleaved row g=(n*2+b) -> [b][n][c]
            off = (size_t)(g & 1) * NNODES * CDIM + (size_t)(g >> 1) * CDIM + ct * 16 + l15;
          } else {
            off = (size_t)g * CDIM + ct * 16 + l15;
          }
          out[off] = (OT)(acc[rt][ct][r] + b2v);
        }
      }
    }
  }
}

extern "C" void kernel_launch(void* const* d_in, const int* in_sizes, int n_in,
                              void* d_out, int out_size, void* d_ws, size_t ws_size,
                              hipStream_t stream) {
  const float* x0 = (const float*)d_in[0];
  const int* ei = (const int*)d_in[1];
  const float* W1_0 = (const float*)d_in[2];
  const float* b1_0 = (const float*)d_in[3];
  const float* W2_0 = (const float*)d_in[4];
  const float* b2_0 = (const float*)d_in[5];
  const float* W1_1 = (const float*)d_in[6];
  const float* b1_1 = (const float*)d_in[7];
  const float* W2_1 = (const float*)d_in[8];
  const float* b2_1 = (const float*)d_in[9];
  float* out = (float*)d_out;

  // workspace layout
  _Float16* xh = (_Float16*)d_ws;                  // ROWS*CDIM interleaved (25.6 MB)
  _Float16* hh = xh + (size_t)ROWS * CDIM;         // ROWS*CDIM interleaved (25.6 MB)
  _Float16* wpk0 = hh + (size_t)ROWS * CDIM;       // 131072 halfs
  _Float16* wpk1 = wpk0 + 131072;                  // 131072 halfs
  int* counts = (int*)(wpk1 + 131072);             // N
  int* offsets = counts + NNODES;                  // N+1
  int* cursor = offsets + NNODES + 1;              // N
  int* col = cursor + NNODES;                      // E

  const int eBlocks = (NEDGES + 255) / 256;
  const int aggBlocks = (NNODES + 3) / 4;    // 12500, one wave per node
  const int mlpBlocks = (ROWS + 127) / 128;  // 782

  // CSR build
  hipMemsetAsync(counts, 0, NNODES * sizeof(int), stream);
  hist_k<<<eBlocks, 256, 0, stream>>>(ei, counts);
  scan_k<<<1, 1024, 0, stream>>>(counts, offsets, cursor);
  fill_k<<<eBlocks, 256, 0, stream>>>(ei, cursor, col);

  // weight pre-pack
  pack_mlp<<<64, 256, 0, stream>>>(W1_0, W2_0, wpk0);
  pack_mlp<<<64, 256, 0, stream>>>(W1_1, W2_1, wpk1);

  // x -> fp16 interleaved
  cvt16i_k<<<2048, 256, 0, stream>>>(x0, xh);

  // layer 0: agg(xh) -> hh ; mlp(hh) -> xh (fp16 y1, interleaved)
  aggi_k<<<aggBlocks, 256, 0, stream>>>(xh, offsets, col, hh);
  mlp_v3<_Float16, false><<<mlpBlocks, 256, 0, stream>>>(hh, wpk0, b1_0, b2_0, xh);
  // layer 1: agg(xh=y1) -> hh ; mlp(hh) -> out (fp32, [b][n][c])
  aggi_k<<<aggBlocks, 256, 0, stream>>>(xh, offsets, col, hh);
  mlp_v3<float, true><<<mlpBlocks, 256, 0, stream>>>(hh, wpk1, b1_1, b2_1, out);
}

// Round 8
// 338.408 us; speedup vs baseline: 19.1643x; 1.0864x over previous
//
#include <hip/hip_runtime.h>

#define CDIM 128
#define HDIM 512
#define NB 2
#define NNODES 50000
#define NEDGES 800000
#define ROWS (NB * NNODES)

typedef _Float16 half8 __attribute__((ext_vector_type(8)));
typedef _Float16 half4 __attribute__((ext_vector_type(4)));
typedef float f32x4 __attribute__((ext_vector_type(4)));

__device__ __forceinline__ f32x4 mfma_f16(half8 a, half8 b, f32x4 c) {
  return __builtin_amdgcn_mfma_f32_16x16x32_f16(a, b, c, 0, 0, 0);
}

#define GLOAD_LDS16(g, l)                                                      \
  __builtin_amdgcn_global_load_lds(                                            \
      (const __attribute__((address_space(1))) void*)(g),                      \
      (__attribute__((address_space(3))) void*)(l), 16, 0, 0)

// ---------------- CSR build ----------------
__global__ void hist_k(const int* __restrict__ ei, int* __restrict__ counts) {
  int e = blockIdx.x * 256 + threadIdx.x;
  if (e < NEDGES) atomicAdd(&counts[ei[NEDGES + e]], 1);
}

// parallel scan, 3 dispatches: 13 blocks x 4096 counts each
#define SC_BLOCKS 13

__global__ __launch_bounds__(256) void scan1_k(const int* __restrict__ counts,
                                               int* __restrict__ bsum) {
  __shared__ int ws[4];
  int i0 = blockIdx.x * 4096 + threadIdx.x * 16;
  int s = 0;
#pragma unroll
  for (int k = 0; k < 16; ++k) {
    int i = i0 + k;
    s += (i < NNODES) ? counts[i] : 0;
  }
#pragma unroll
  for (int off = 1; off < 64; off <<= 1) s += __shfl_down(s, off);
  if ((threadIdx.x & 63) == 0) ws[threadIdx.x >> 6] = s;
  __syncthreads();
  if (threadIdx.x == 0) bsum[blockIdx.x] = ws[0] + ws[1] + ws[2] + ws[3];
}

__global__ void scan2_k(const int* __restrict__ bsum, int* __restrict__ bbase,
                        int* __restrict__ offsets) {
  int run = 0;
  for (int b = 0; b < SC_BLOCKS; ++b) {
    bbase[b] = run;
    run += bsum[b];
  }
  offsets[NNODES] = run;  // == NEDGES
}

__global__ __launch_bounds__(256) void scan3_k(const int* __restrict__ counts,
                                               const int* __restrict__ bbase,
                                               int* __restrict__ offsets,
                                               int* __restrict__ cursor) {
  __shared__ int sm[256];
  int i0 = blockIdx.x * 4096 + threadIdx.x * 16;
  int v[16];
  int tsum = 0;
#pragma unroll
  for (int k = 0; k < 16; ++k) {
    int i = i0 + k;
    v[k] = (i < NNODES) ? counts[i] : 0;
    tsum += v[k];
  }
  sm[threadIdx.x] = tsum;
  __syncthreads();
  for (int off = 1; off < 256; off <<= 1) {
    int t = (threadIdx.x >= off) ? sm[threadIdx.x - off] : 0;
    __syncthreads();
    sm[threadIdx.x] += t;
    __syncthreads();
  }
  int run = bbase[blockIdx.x] + sm[threadIdx.x] - tsum;
#pragma unroll
  for (int k = 0; k < 16; ++k) {
    int i = i0 + k;
    if (i < NNODES) {
      offsets[i] = run;
      cursor[i] = run;
    }
    run += v[k];
  }
}

__global__ void fill_k(const int* __restrict__ ei, int* __restrict__ cursor,
                       int* __restrict__ col) {
  int e = blockIdx.x * 256 + threadIdx.x;
  if (e < NEDGES) {
    int d = ei[NEDGES + e];
    int p = atomicAdd(&cursor[d], 1);
    col[p] = ei[e];
  }
}

// ---- fp32 [b][n][c] -> fp16 batch-interleaved [n][b][c] ----
__global__ void cvt16i_k(const float* __restrict__ s, _Float16* __restrict__ d) {
  const int PB = NNODES * CDIM;
  int i = blockIdx.x * 256 + threadIdx.x;
  int str = gridDim.x * 256;
  for (; i < ROWS * (CDIM / 8); i += str) {
    size_t flat = (size_t)i * 8;
    int b = (int)(flat / PB);
    size_t r = flat - (size_t)b * PB;
    int n = (int)(r >> 7);
    int c0 = (int)(r & 127);
    float4 f0 = *(const float4*)(s + flat);
    float4 f1 = *(const float4*)(s + flat + 4);
    half8 o;
    o[0] = (_Float16)f0.x; o[1] = (_Float16)f0.y;
    o[2] = (_Float16)f0.z; o[3] = (_Float16)f0.w;
    o[4] = (_Float16)f1.x; o[5] = (_Float16)f1.y;
    o[6] = (_Float16)f1.z; o[7] = (_Float16)f1.w;
    *(half8*)(d + ((size_t)n * 2 + b) * CDIM + c0) = o;
  }
}

// ---- aggregation: one wave per node-pair; 8-edge unroll, 2 accum chains ----
__global__ __launch_bounds__(256) void aggi_k(const _Float16* __restrict__ x,
                                              const int* __restrict__ offs,
                                              const int* __restrict__ col,
                                              _Float16* __restrict__ h) {
  int node = blockIdx.x * 4 + (threadIdx.x >> 6);
  int lane = threadIdx.x & 63;
  if (node >= NNODES) return;
  const half4* xp = (const half4*)x;  // 64 half4 per node-pair
  half4 self = xp[(size_t)node * 64 + lane];
  float a0 = (float)self[0], a1 = (float)self[1], a2 = (float)self[2], a3 = (float)self[3];
  float c0 = 0.f, c1 = 0.f, c2 = 0.f, c3 = 0.f;
  int e = offs[node], e1 = offs[node + 1];
  for (; e + 7 < e1; e += 8) {
    int s0 = col[e], s1 = col[e + 1], s2 = col[e + 2], s3 = col[e + 3];
    int s4 = col[e + 4], s5 = col[e + 5], s6 = col[e + 6], s7 = col[e + 7];
    half4 v0 = xp[(size_t)s0 * 64 + lane];
    half4 v1 = xp[(size_t)s1 * 64 + lane];
    half4 v2 = xp[(size_t)s2 * 64 + lane];
    half4 v3 = xp[(size_t)s3 * 64 + lane];
    half4 v4 = xp[(size_t)s4 * 64 + lane];
    half4 v5 = xp[(size_t)s5 * 64 + lane];
    half4 v6 = xp[(size_t)s6 * 64 + lane];
    half4 v7 = xp[(size_t)s7 * 64 + lane];
    a0 += (float)v0[0] + (float)v1[0] + (float)v2[0] + (float)v3[0];
    a1 += (float)v0[1] + (float)v1[1] + (float)v2[1] + (float)v3[1];
    a2 += (float)v0[2] + (float)v1[2] + (float)v2[2] + (float)v3[2];
    a3 += (float)v0[3] + (float)v1[3] + (float)v2[3] + (float)v3[3];
    c0 += (float)v4[0] + (float)v5[0] + (float)v6[0] + (float)v7[0];
    c1 += (float)v4[1] + (float)v5[1] + (float)v6[1] + (float)v7[1];
    c2 += (float)v4[2] + (float)v5[2] + (float)v6[2] + (float)v7[2];
    c3 += (float)v4[3] + (float)v5[3] + (float)v6[3] + (float)v7[3];
  }
  for (; e + 1 < e1; e += 2) {
    int s0 = col[e], s1 = col[e + 1];
    half4 v0 = xp[(size_t)s0 * 64 + lane];
    half4 v1 = xp[(size_t)s1 * 64 + lane];
    a0 += (float)v0[0]; a1 += (float)v0[1];
    a2 += (float)v0[2]; a3 += (float)v0[3];
    c0 += (float)v1[0]; c1 += (float)v1[1];
    c2 += (float)v1[2]; c3 += (float)v1[3];
  }
  if (e < e1) {
    int s0 = col[e];
    half4 v0 = xp[(size_t)s0 * 64 + lane];
    a0 += (float)v0[0]; a1 += (float)v0[1];
    a2 += (float)v0[2]; a3 += (float)v0[3];
  }
  half4 r;
  r[0] = (_Float16)(a0 + c0);
  r[1] = (_Float16)(a1 + c1);
  r[2] = (_Float16)(a2 + c2);
  r[3] = (_Float16)(a3 + c3);
  ((half4*)h)[(size_t)node * 64 + lane] = r;
}

// ---------------- weight pre-pack into per-chunk merged fragment layout ------
__global__ void pack_mlp(const float* __restrict__ W1, const float* __restrict__ W2,
                         _Float16* __restrict__ dst) {
  int tid = blockIdx.x * 256 + threadIdx.x;  // 0..16383
  if (tid >= 16384) return;
  int l = tid & 63;
  int g = (tid >> 6) & 7;
  int c = (tid >> 9) & 15;
  int isW2 = tid >> 13;
  int lg = l >> 4, l15 = l & 15;
  _Float16* o;
  if (!isW2) {
    int jt = g >> 2, ks = g & 3;
    int k0 = ks * 32 + lg * 8;
    int n = c * 32 + jt * 16 + l15;
    o = dst + (size_t)c * 8192 + g * 512 + l * 8;
#pragma unroll
    for (int i = 0; i < 8; ++i) o[i] = (_Float16)W1[(size_t)(k0 + i) * HDIM + n];
  } else {
    int k0 = c * 32 + lg * 8;
    int n = g * 16 + l15;
    o = dst + (size_t)c * 8192 + 4096 + g * 512 + l * 8;
#pragma unroll
    for (int i = 0; i < 8; ++i) o[i] = (_Float16)W2[(size_t)(k0 + i) * CDIM + n];
  }
}

// ---------------- fused MLP: LDS-shared W, double-buffered staging ----------
template <typename OT, bool REMAP>
__global__ __launch_bounds__(256, 4) void mlp_v3(
    const _Float16* __restrict__ hin, const _Float16* __restrict__ wpk,
    const float* __restrict__ b1, const float* __restrict__ b2,
    OT* __restrict__ out) {
  __shared__ alignas(16) _Float16 wbuf[2][8192];
  __shared__ alignas(16) _Float16 tbuf[4][32 * 32];

  const int tidx = threadIdx.x;
  const int lane = tidx & 63;
  const int wid = tidx >> 6;
  const int l15 = lane & 15, lg = lane >> 4;
  const long long r0 = (long long)blockIdx.x * 128 + wid * 32;

  half8 A[2][4];
#pragma unroll
  for (int rt = 0; rt < 2; ++rt) {
    long long row = r0 + rt * 16 + l15;
    if (row >= ROWS) row = ROWS - 1;
    const _Float16* hp = hin + row * CDIM + lg * 8;
#pragma unroll
    for (int ks = 0; ks < 4; ++ks) A[rt][ks] = *(const half8*)(hp + ks * 32);
  }

  {
    const _Float16* src = wpk;
#pragma unroll
    for (int q = 0; q < 4; ++q) {
      int s = wid * 4 + q;
      GLOAD_LDS16(src + s * 512 + lane * 8, &wbuf[0][s * 512]);
    }
  }
  __syncthreads();

  f32x4 acc[2][8];
#pragma unroll
  for (int rt = 0; rt < 2; ++rt)
#pragma unroll
    for (int ct = 0; ct < 8; ++ct) acc[rt][ct] = (f32x4){0.f, 0.f, 0.f, 0.f};

  _Float16* tw = &tbuf[wid][0];

  for (int c = 0; c < 16; ++c) {
    const int cur = c & 1;
    if (c + 1 < 16) {
      const _Float16* src = wpk + (size_t)(c + 1) * 8192;
#pragma unroll
      for (int q = 0; q < 4; ++q) {
        int s = wid * 4 + q;
        GLOAD_LDS16(src + s * 512 + lane * 8, &wbuf[cur ^ 1][s * 512]);
      }
    }
    const _Float16* w1c = &wbuf[cur][0];
    const _Float16* w2c = &wbuf[cur][4096];

#pragma unroll
    for (int jt = 0; jt < 2; ++jt) {
      f32x4 t0 = (f32x4){0.f, 0.f, 0.f, 0.f};
      f32x4 t1 = (f32x4){0.f, 0.f, 0.f, 0.f};
#pragma unroll
      for (int ks = 0; ks < 4; ++ks) {
        half8 b = *(const half8*)(w1c + (jt * 4 + ks) * 512 + lane * 8);
        t0 = mfma_f16(A[0][ks], b, t0);
        t1 = mfma_f16(A[1][ks], b, t1);
      }
      float bb = b1[c * 32 + jt * 16 + l15];
      int j = jt * 16 + l15;
#pragma unroll
      for (int r = 0; r < 4; ++r) {
        int n0 = lg * 4 + r;
        tw[n0 * 32 + (j ^ (((n0 >> 2) & 3) << 3))] = (_Float16)fmaxf(t0[r] + bb, 0.f);
        int n1 = 16 + lg * 4 + r;
        tw[n1 * 32 + (j ^ (((n1 >> 2) & 3) << 3))] = (_Float16)fmaxf(t1[r] + bb, 0.f);
      }
    }

    half8 ta0, ta1;
    {
      int n = l15;
      ta0 = *(const half8*)(tw + n * 32 + ((lg * 8) ^ (((n >> 2) & 3) << 3)));
      n = 16 + l15;
      ta1 = *(const half8*)(tw + n * 32 + ((lg * 8) ^ (((n >> 2) & 3) << 3)));
    }
#pragma unroll
    for (int ct = 0; ct < 8; ++ct) {
      half8 b = *(const half8*)(w2c + ct * 512 + lane * 8);
      acc[0][ct] = mfma_f16(ta0, b, acc[0][ct]);
      acc[1][ct] = mfma_f16(ta1, b, acc[1][ct]);
    }
    __syncthreads();
  }

#pragma unroll
  for (int ct = 0; ct < 8; ++ct) {
    float b2v = b2[ct * 16 + l15];
#pragma unroll
    for (int rt = 0; rt < 2; ++rt) {
#pragma unroll
      for (int r = 0; r < 4; ++r) {
        long long g = r0 + rt * 16 + lg * 4 + r;
        if (g < ROWS) {
          size_t off;
          if (REMAP) {
            off = (size_t)(g & 1) * NNODES * CDIM + (size_t)(g >> 1) * CDIM + ct * 16 + l15;
          } else {
            off = (size_t)g * CDIM + ct * 16 + l15;
          }
          out[off] = (OT)(acc[rt][ct][r] + b2v);
        }
      }
    }
  }
}

extern "C" void kernel_launch(void* const* d_in, const int* in_sizes, int n_in,
                              void* d_out, int out_size, void* d_ws, size_t ws_size,
                              hipStream_t stream) {
  const float* x0 = (const float*)d_in[0];
  const int* ei = (const int*)d_in[1];
  const float* W1_0 = (const float*)d_in[2];
  const float* b1_0 = (const float*)d_in[3];
  const float* W2_0 = (const float*)d_in[4];
  const float* b2_0 = (const float*)d_in[5];
  const float* W1_1 = (const float*)d_in[6];
  const float* b1_1 = (const float*)d_in[7];
  const float* W2_1 = (const float*)d_in[8];
  const float* b2_1 = (const float*)d_in[9];
  float* out = (float*)d_out;

  // workspace layout
  _Float16* xh = (_Float16*)d_ws;                  // ROWS*CDIM interleaved (25.6 MB)
  _Float16* hh = xh + (size_t)ROWS * CDIM;         // ROWS*CDIM interleaved (25.6 MB)
  _Float16* wpk0 = hh + (size_t)ROWS * CDIM;       // 131072 halfs
  _Float16* wpk1 = wpk0 + 131072;                  // 131072 halfs
  int* counts = (int*)(wpk1 + 131072);             // N
  int* offsets = counts + NNODES;                  // N+1
  int* cursor = offsets + NNODES + 1;              // N
  int* col = cursor + NNODES;                      // E
  int* bsum = col + NEDGES;                        // 16
  int* bbase = bsum + 16;                          // 16

  const int eBlocks = (NEDGES + 255) / 256;
  const int aggBlocks = (NNODES + 3) / 4;    // 12500
  const int mlpBlocks = (ROWS + 127) / 128;  // 782

  // CSR build
  hipMemsetAsync(counts, 0, NNODES * sizeof(int), stream);
  hist_k<<<eBlocks, 256, 0, stream>>>(ei, counts);
  scan1_k<<<SC_BLOCKS, 256, 0, stream>>>(counts, bsum);
  scan2_k<<<1, 1, 0, stream>>>(bsum, bbase, offsets);
  scan3_k<<<SC_BLOCKS, 256, 0, stream>>>(counts, bbase, offsets, cursor);
  fill_k<<<eBlocks, 256, 0, stream>>>(ei, cursor, col);

  // weight pre-pack
  pack_mlp<<<64, 256, 0, stream>>>(W1_0, W2_0, wpk0);
  pack_mlp<<<64, 256, 0, stream>>>(W1_1, W2_1, wpk1);

  // x -> fp16 interleaved
  cvt16i_k<<<2048, 256, 0, stream>>>(x0, xh);

  // layer 0
  aggi_k<<<aggBlocks, 256, 0, stream>>>(xh, offsets, col, hh);
  mlp_v3<_Float16, false><<<mlpBlocks, 256, 0, stream>>>(hh, wpk0, b1_0, b2_0, xh);
  // layer 1
  aggi_k<<<aggBlocks, 256, 0, stream>>>(xh, offsets, col, hh);
  mlp_v3<float, true><<<mlpBlocks, 256, 0, stream>>>(hh, wpk1, b1_1, b2_1, out);
}